// Round 11
// baseline (825.406 us; speedup 1.0000x reference)
//
#include <hip/hip_runtime.h>
#include <hip/hip_bf16.h>
#include <math.h>

#define D_MODEL 1024
#define D_STATE 16
#define D_INNER 2048
#define DT_RANK 64
#define BATCH   2
#define SEQLEN  2048
#define NPROJ   96   // DT_RANK + 2*D_STATE
#define NCHUNK  16
#define CHUNK   128  // SEQLEN / NCHUNK

typedef __attribute__((ext_vector_type(8))) __bf16 bf16x8;
typedef __attribute__((ext_vector_type(4))) float f32x4;

__device__ __forceinline__ float silu_f(float x) { return x / (1.f + __expf(-x)); }

__device__ __forceinline__ void gload_lds16(const void* g, void* l) {
    __builtin_amdgcn_global_load_lds((const __attribute__((address_space(1))) void*)g,
                                     (__attribute__((address_space(3))) void*)l, 16, 0, 0);
}

// ---------------- bf16 MFMA NT GEMM: C[m,n] = sum_k A[m,k]*B[n,k] -------------
template<int RELU, int OUT_BF16>
__global__ __launch_bounds__(256) void gemm_bf16_k(
    const __bf16* __restrict__ A, const __bf16* __restrict__ B, void* __restrict__ Cv,
    int K, int lda, int ldb, int ldc, long long sB, long long sC)
{
    __shared__ alignas(16) __bf16 As[128 * 32];
    __shared__ alignas(16) __bf16 Bs[128 * 32];
    const int bz = blockIdx.z;
    B += (long long)bz * sB;
    const int m0 = blockIdx.y * 128, n0 = blockIdx.x * 128;
    const int tid = threadIdx.x;
    const int lane = tid & 63;
    const int wv = tid >> 6;
    const int wr = wv >> 1, wc = wv & 1;

    f32x4 acc[4][4];
    #pragma unroll
    for (int i = 0; i < 4; ++i)
        #pragma unroll
        for (int j = 0; j < 4; ++j) acc[i][j] = (f32x4){0.f, 0.f, 0.f, 0.f};

    const int ko = (lane >> 4) * 8;
    const int fr = lane & 15;

    for (int k0 = 0; k0 < K; k0 += 32) {
        #pragma unroll
        for (int q = 0; q < 2; ++q) {
            int f = tid + q * 256;
            int row = f >> 2, c16 = f & 3;
            gload_lds16(A + (long long)(m0 + row) * lda + k0 + c16 * 8, As + f * 8);
            gload_lds16(B + (long long)(n0 + row) * ldb + k0 + c16 * 8, Bs + f * 8);
        }
        __syncthreads();
        bf16x8 a[4], b[4];
        #pragma unroll
        for (int i = 0; i < 4; ++i) {
            a[i] = *(const bf16x8*)(As + (wr * 64 + i * 16 + fr) * 32 + ko);
            b[i] = *(const bf16x8*)(Bs + (wc * 64 + i * 16 + fr) * 32 + ko);
        }
        #pragma unroll
        for (int i = 0; i < 4; ++i)
            #pragma unroll
            for (int j = 0; j < 4; ++j)
                acc[i][j] = __builtin_amdgcn_mfma_f32_16x16x32_bf16(a[i], b[j], acc[i][j], 0, 0, 0);
        __syncthreads();
    }

    #pragma unroll
    for (int i = 0; i < 4; ++i) {
        const int row = m0 + wr * 64 + i * 16 + (lane >> 4) * 4;
        #pragma unroll
        for (int j = 0; j < 4; ++j) {
            const int col = n0 + wc * 64 + j * 16 + fr;
            #pragma unroll
            for (int r = 0; r < 4; ++r) {
                float v = acc[i][j][r];
                if (RELU) v = fmaxf(v, 0.f);
                if (OUT_BF16)
                    ((__bf16*)Cv)[(long long)bz * sC + (long long)(row + r) * ldc + col] = (__bf16)v;
                else
                    ((float*)Cv)[(long long)bz * sC + (long long)(row + r) * ldc + col] = v;
            }
        }
    }
}

// ---------------- f32 -> bf16 pack (8 per thread) ----------------
__global__ void cvt_bf16_k(const float* __restrict__ in, __bf16* __restrict__ out, int n8) {
    int i = blockIdx.x * 256 + threadIdx.x;
    if (i >= n8) return;
    const f32x4* p = (const f32x4*)in + (long long)i * 2;
    f32x4 v0 = p[0], v1 = p[1];
    bf16x8 o;
    o[0] = (__bf16)v0[0]; o[1] = (__bf16)v0[1]; o[2] = (__bf16)v0[2]; o[3] = (__bf16)v0[3];
    o[4] = (__bf16)v1[0]; o[5] = (__bf16)v1[1]; o[6] = (__bf16)v1[2]; o[7] = (__bf16)v1[3];
    ((bf16x8*)out)[i] = o;
}

// ---------------- generic fp32 NT GEMM (kept for small dt GEMM) ----------------
template<int RELU>
__global__ __launch_bounds__(256) void gemm_nt_k(
    const float* __restrict__ A, const float* __restrict__ B, float* __restrict__ C,
    int M, int N, int K, int lda, int ldb, int ldc,
    long long sA, long long sB, long long sC)
{
    __shared__ float As[16][68];
    __shared__ float Bs[16][68];
    const int bz = blockIdx.z;
    A += (long long)bz * sA; B += (long long)bz * sB; C += (long long)bz * sC;
    const int m0 = blockIdx.y * 64, n0 = blockIdx.x * 64;
    const int tid = threadIdx.x;
    const int lk = tid & 15, lr = tid >> 4;
    const int tx = tid & 15, ty = tid >> 4;
    float acc[4][4] = {};
    for (int k0 = 0; k0 < K; k0 += 16) {
        #pragma unroll
        for (int q = 0; q < 4; ++q) {
            int i = lr + q * 16;
            As[lk][i] = A[(long long)(m0 + i) * lda + k0 + lk];
            Bs[lk][i] = B[(long long)(n0 + i) * ldb + k0 + lk];
        }
        __syncthreads();
        #pragma unroll
        for (int k = 0; k < 16; ++k) {
            float a[4], b[4];
            #pragma unroll
            for (int j = 0; j < 4; ++j) { a[j] = As[k][ty*4+j]; b[j] = Bs[k][tx*4+j]; }
            #pragma unroll
            for (int i = 0; i < 4; ++i)
                #pragma unroll
                for (int j = 0; j < 4; ++j) acc[i][j] += a[i] * b[j];
        }
        __syncthreads();
    }
    #pragma unroll
    for (int i = 0; i < 4; ++i)
        #pragma unroll
        for (int j = 0; j < 4; ++j) {
            float v = acc[i][j];
            if (RELU) v = fmaxf(v, 0.f);
            C[(long long)(m0 + ty*4 + i) * ldc + n0 + tx*4 + j] = v;
        }
}

// ---------------- Aneg = -exp(A_log) ----------------
__global__ void aneg_k(const float* __restrict__ A_log, float* __restrict__ Aneg) {
    int i = blockIdx.x * 256 + threadIdx.x;
    if (i < D_INNER * D_STATE) Aneg[i] = -expf(A_log[i]);
}

// ---------------- depthwise causal conv(4) + bias + SiLU ----------------
__global__ void conv_silu_k(const float* __restrict__ xz, const float* __restrict__ cw,
                            const float* __restrict__ cb, float* __restrict__ u)
{
    int idx = blockIdx.x * 256 + threadIdx.x;
    int l = idx & (SEQLEN - 1);
    int d = (idx >> 11) & (D_INNER - 1);
    int b = idx >> 22;
    const float* xi = xz + ((long long)b * 2 * D_INNER + d) * SEQLEN;
    float acc = cb[d];
    #pragma unroll
    for (int k = 0; k < 4; ++k) {
        int t = l + k - 3;
        if (t >= 0) acc += xi[t] * cw[d * 4 + k];
    }
    u[idx] = silu_f(acc);
}

// ---------------- x_dbl[b,l,e] = sum_d u[b,d,l] * W_x[e,d] ----------------
// 512 blocks (2/CU), float4 staging, reg double-buffer, Ws pad 97 (mod32=1:
// conflict-free staging writes). Compute reads are wave-uniform broadcasts.
__global__ __launch_bounds__(256) void xdbl_k(const float* __restrict__ u,
    const float* __restrict__ Wx, float* __restrict__ xdbl)
{
    __shared__ float Us[32][65];
    __shared__ float Ws[32][97];
    const int b = blockIdx.z;
    const int l0 = blockIdx.x * 64;
    const int kbase = blockIdx.y * 256;
    const int tid = threadIdx.x;
    const int lx = tid & 63, eg = tid >> 6;
    const int ukk = tid >> 4;          // 0..15 (+16 for q=1)
    const int ul4 = tid & 15;
    const int we = tid >> 3;           // 0..31 (+32q)
    const int wj = tid & 7;

    float acc[24] = {};
    float4 ru0, ru1, rw0, rw1, rw2;

    {
        const int k0 = kbase;
        ru0 = ((const float4*)(u + ((long long)(b * D_INNER + k0 + ukk)) * SEQLEN + l0))[ul4];
        ru1 = ((const float4*)(u + ((long long)(b * D_INNER + k0 + ukk + 16)) * SEQLEN + l0))[ul4];
        rw0 = ((const float4*)(Wx + (long long)(we) * D_INNER + k0))[wj];
        rw1 = ((const float4*)(Wx + (long long)(we + 32) * D_INNER + k0))[wj];
        rw2 = ((const float4*)(Wx + (long long)(we + 64) * D_INNER + k0))[wj];
    }

    for (int kc = 0; kc < 8; ++kc) {
        Us[ukk][ul4*4+0] = ru0.x; Us[ukk][ul4*4+1] = ru0.y;
        Us[ukk][ul4*4+2] = ru0.z; Us[ukk][ul4*4+3] = ru0.w;
        Us[ukk+16][ul4*4+0] = ru1.x; Us[ukk+16][ul4*4+1] = ru1.y;
        Us[ukk+16][ul4*4+2] = ru1.z; Us[ukk+16][ul4*4+3] = ru1.w;
        Ws[wj*4+0][we] = rw0.x; Ws[wj*4+1][we] = rw0.y;
        Ws[wj*4+2][we] = rw0.z; Ws[wj*4+3][we] = rw0.w;
        Ws[wj*4+0][we+32] = rw1.x; Ws[wj*4+1][we+32] = rw1.y;
        Ws[wj*4+2][we+32] = rw1.z; Ws[wj*4+3][we+32] = rw1.w;
        Ws[wj*4+0][we+64] = rw2.x; Ws[wj*4+1][we+64] = rw2.y;
        Ws[wj*4+2][we+64] = rw2.z; Ws[wj*4+3][we+64] = rw2.w;
        __syncthreads();
        if (kc + 1 < 8) {
            const int kn = kbase + (kc + 1) * 32;
            ru0 = ((const float4*)(u + ((long long)(b * D_INNER + kn + ukk)) * SEQLEN + l0))[ul4];
            ru1 = ((const float4*)(u + ((long long)(b * D_INNER + kn + ukk + 16)) * SEQLEN + l0))[ul4];
            rw0 = ((const float4*)(Wx + (long long)(we) * D_INNER + kn))[wj];
            rw1 = ((const float4*)(Wx + (long long)(we + 32) * D_INNER + kn))[wj];
            rw2 = ((const float4*)(Wx + (long long)(we + 64) * D_INNER + kn))[wj];
        }
        #pragma unroll
        for (int kk = 0; kk < 32; ++kk) {
            float a = Us[kk][lx];
            #pragma unroll
            for (int j = 0; j < 24; ++j) acc[j] += a * Ws[kk][eg * 24 + j];
        }
        __syncthreads();
    }
    #pragma unroll
    for (int j = 0; j < 24; ++j)
        atomicAdd(&xdbl[((long long)b * SEQLEN + l0 + lx) * NPROJ + eg * 24 + j], acc[j]);
}

// ---------------- delta = softplus(dt + b_dt) in place ----------------
__global__ void softplus_k(float* __restrict__ dtb, const float* __restrict__ b_dt) {
    int idx = blockIdx.x * 256 + threadIdx.x;
    int d = (idx >> 11) & (D_INNER - 1);
    float v = dtb[idx] + b_dt[d];
    dtb[idx] = fmaxf(v, 0.f) + log1pf(expf(-fabsf(v)));
}

// ======== chunked selective scan: time-parallel via associative combine =======
__global__ __launch_bounds__(64, 1) void scan_p1_k(const float* __restrict__ delta,
    const float* __restrict__ u, const float* __restrict__ xdbl,
    const float* __restrict__ Aneg, float* __restrict__ chA, float* __restrict__ chS)
{
    const int q = threadIdx.x >> 4;
    const int n = threadIdx.x & 15;
    const int gg = blockIdx.x * 4 + q;
    const int g = gg >> 4, c = gg & (NCHUNK - 1);
    const int b = g >> 11, d = g & (D_INNER - 1);
    const float a = Aneg[d * D_STATE + n];
    const long long base = (long long)g * SEQLEN + c * CHUNK;
    const float4* dv = (const float4*)(delta + base);
    const float4* uv = (const float4*)(u + base);
    const float* xb = xdbl + ((long long)b * SEQLEN + c * CHUNK) * NPROJ + DT_RANK + n;

    float4 pd[4], pu[4];
    float pB[16];
    #pragma unroll
    for (int i = 0; i < 4; ++i) { pd[i] = dv[i]; pu[i] = uv[i]; }
    #pragma unroll
    for (int i = 0; i < 16; ++i) pB[i] = xb[i * NPROJ];

    float s = 0.f, ap = 1.f;
    for (int t0 = 0; t0 < CHUNK; t0 += 16) {
        float cd[16], cu[16], cB[16];
        #pragma unroll
        for (int i = 0; i < 4; ++i) {
            cd[4*i] = pd[i].x; cd[4*i+1] = pd[i].y; cd[4*i+2] = pd[i].z; cd[4*i+3] = pd[i].w;
            cu[4*i] = pu[i].x; cu[4*i+1] = pu[i].y; cu[4*i+2] = pu[i].z; cu[4*i+3] = pu[i].w;
        }
        #pragma unroll
        for (int i = 0; i < 16; ++i) cB[i] = pB[i];
        if (t0 + 16 < CHUNK) {
            const int nb = (t0 >> 2) + 4;
            #pragma unroll
            for (int i = 0; i < 4; ++i) { pd[i] = dv[nb + i]; pu[i] = uv[nb + i]; }
            const float* xn = xb + (t0 + 16) * NPROJ;
            #pragma unroll
            for (int i = 0; i < 16; ++i) pB[i] = xn[i * NPROJ];
        }
        float dA[16], wB[16];
        #pragma unroll
        for (int i = 0; i < 16; ++i) {
            dA[i] = __expf(cd[i] * a);
            wB[i] = cd[i] * cu[i] * cB[i];
        }
        #pragma unroll
        for (int i = 0; i < 16; ++i) {
            s = dA[i] * s + wB[i];
            ap *= dA[i];
        }
    }
    chA[(long long)gg * 16 + n] = ap;
    chS[(long long)gg * 16 + n] = s;
}

__global__ void scan_comb_k(const float* __restrict__ chA, const float* __restrict__ chS,
                            float* __restrict__ sinit)
{
    int idx = blockIdx.x * 256 + threadIdx.x;      // (g, n), 65536 total
    int g = idx >> 4, n = idx & 15;
    const float* A = chA + (long long)g * (NCHUNK * 16) + n;
    const float* S = chS + (long long)g * (NCHUNK * 16) + n;
    float av[NCHUNK], sv[NCHUNK];
    #pragma unroll
    for (int c = 0; c < NCHUNK; ++c) { av[c] = A[c * 16]; sv[c] = S[c * 16]; }
    float* si = sinit + (long long)g * (NCHUNK * 16) + n;
    float carry = 0.f;
    #pragma unroll
    for (int c = 0; c < NCHUNK; ++c) {
        si[c * 16] = carry;
        carry = sv[c] + av[c] * carry;
    }
}

__global__ __launch_bounds__(64, 1) void scan_p3_k(const float* __restrict__ delta,
    const float* __restrict__ u, const float* __restrict__ xdbl,
    const float* __restrict__ Aneg, const float* __restrict__ sinit, float* __restrict__ y)
{
    __shared__ float lp[4][16][17];
    const int q = threadIdx.x >> 4;
    const int n = threadIdx.x & 15;
    const int gg = blockIdx.x * 4 + q;
    const int g = gg >> 4, c = gg & (NCHUNK - 1);
    const int b = g >> 11, d = g & (D_INNER - 1);
    const float a = Aneg[d * D_STATE + n];
    const long long base = (long long)g * SEQLEN + c * CHUNK;
    const float4* dv = (const float4*)(delta + base);
    const float4* uv = (const float4*)(u + base);
    const float* xb = xdbl + ((long long)b * SEQLEN + c * CHUNK) * NPROJ + DT_RANK + n;
    float* yl = y + base;

    float4 pd[4], pu[4];
    float pB[16], pC[16];
    #pragma unroll
    for (int i = 0; i < 4; ++i) { pd[i] = dv[i]; pu[i] = uv[i]; }
    #pragma unroll
    for (int i = 0; i < 16; ++i) { pB[i] = xb[i * NPROJ]; pC[i] = xb[i * NPROJ + D_STATE]; }

    float s = sinit[(long long)gg * 16 + n];
    for (int t0 = 0; t0 < CHUNK; t0 += 16) {
        float cd[16], cu[16], cB[16], cC[16];
        #pragma unroll
        for (int i = 0; i < 4; ++i) {
            cd[4*i] = pd[i].x; cd[4*i+1] = pd[i].y; cd[4*i+2] = pd[i].z; cd[4*i+3] = pd[i].w;
            cu[4*i] = pu[i].x; cu[4*i+1] = pu[i].y; cu[4*i+2] = pu[i].z; cu[4*i+3] = pu[i].w;
        }
        #pragma unroll
        for (int i = 0; i < 16; ++i) { cB[i] = pB[i]; cC[i] = pC[i]; }
        if (t0 + 16 < CHUNK) {
            const int nb = (t0 >> 2) + 4;
            #pragma unroll
            for (int i = 0; i < 4; ++i) { pd[i] = dv[nb + i]; pu[i] = uv[nb + i]; }
            const float* xn = xb + (t0 + 16) * NPROJ;
            #pragma unroll
            for (int i = 0; i < 16; ++i) { pB[i] = xn[i * NPROJ]; pC[i] = xn[i * NPROJ + D_STATE]; }
        }
        float dA[16], wB[16];
        #pragma unroll
        for (int i = 0; i < 16; ++i) {
            dA[i] = __expf(cd[i] * a);
            wB[i] = cd[i] * cu[i] * cB[i];
        }
        #pragma unroll
        for (int i = 0; i < 16; ++i) {
            s = dA[i] * s + wB[i];
            lp[q][n][i] = s * cC[i];
        }
        __syncthreads();
        float v[16];
        #pragma unroll
        for (int j = 0; j < 16; ++j) v[j] = lp[q][j][n];
        float acc = 0.f;
        #pragma unroll
        for (int j = 0; j < 16; ++j) acc += v[j];
        yl[t0 + n] = acc;
        __syncthreads();
    }
}

// ---------------- S[b,l] = sum_d Dp[d]*u[b,d,l] ----------------
__global__ void ssum_k(const float* __restrict__ u, const float* __restrict__ Dp,
                       float* __restrict__ S)
{
    int li = blockIdx.x * 256 + threadIdx.x;
    int c = blockIdx.y;
    int b = li >> 11, l = li & (SEQLEN - 1);
    const float* up = u + (long long)b * D_INNER * SEQLEN + l;
    float acc = 0.f;
    for (int d = c * 256; d < c * 256 + 256; ++d)
        acc += Dp[d] * up[(long long)d * SEQLEN];
    atomicAdd(&S[li], acc);
}

// ---------------- y=(y+Dp*u)*silu(z), transposed into ycat16[...,:2048] -------
__global__ __launch_bounds__(256) void ytrans_k(const float* __restrict__ ysc,
    const float* __restrict__ u, const float* __restrict__ xz,
    const float* __restrict__ Dp, __bf16* __restrict__ ycat)
{
    __shared__ float tile[32][33];
    const int b = blockIdx.z;
    const int d0 = blockIdx.y * 32, l0 = blockIdx.x * 32;
    const int lx = threadIdx.x, dy = threadIdx.y;
    #pragma unroll
    for (int j = 0; j < 4; ++j) {
        int d = d0 + dy + j * 8;
        long long i  = ((long long)b * D_INNER + d) * SEQLEN + l0 + lx;
        long long iz = ((long long)b * 2 * D_INNER + D_INNER + d) * SEQLEN + l0 + lx;
        tile[dy + j * 8][lx] = (ysc[i] + Dp[d] * u[i]) * silu_f(xz[iz]);
    }
    __syncthreads();
    #pragma unroll
    for (int j = 0; j < 4; ++j) {
        int l = l0 + dy + j * 8;
        ycat[((long long)b * SEQLEN + l) * (2 * D_INNER) + d0 + lx] = (__bf16)tile[lx][dy + j * 8];
    }
}

// ---------------- y_t -> ycat16[...,2048:] ----------------
__global__ __launch_bounds__(256) void yt_k(const float* __restrict__ xdbl,
    const float* __restrict__ Aneg, const float* __restrict__ S, __bf16* __restrict__ ycat)
{
    __shared__ float Cs[16][33];
    __shared__ float An[16][64];
    __shared__ float Sv[32];
    const int b = blockIdx.z;
    const int d0 = blockIdx.y * 64, l0 = blockIdx.x * 32;
    const int tid = threadIdx.x;
    for (int f = tid; f < 512; f += 256) {
        int n = f & 15, l = f >> 4;
        Cs[n][l] = xdbl[((long long)b * SEQLEN + l0 + l) * NPROJ + DT_RANK + D_STATE + n];
    }
    for (int f = tid; f < 1024; f += 256) {
        int n = f & 15, d = f >> 4;
        An[n][d] = Aneg[(d0 + d) * D_STATE + n];
    }
    if (tid < 32) Sv[tid] = S[b * SEQLEN + l0 + tid];
    __syncthreads();
    const int dx = tid & 63, lg = tid >> 6;
    #pragma unroll
    for (int j = 0; j < 8; ++j) {
        int l = lg * 8 + j;
        float acc = Sv[l];
        #pragma unroll
        for (int n = 0; n < 16; ++n) acc += Cs[n][l] * An[n][dx];
        ycat[((long long)b * SEQLEN + l0 + l) * (2 * D_INNER) + D_INNER + d0 + dx] = (__bf16)acc;
    }
}

extern "C" void kernel_launch(void* const* d_in, const int* in_sizes, int n_in,
                              void* d_out, int out_size, void* d_ws, size_t ws_size,
                              hipStream_t stream)
{
    const float* x      = (const float*)d_in[0];
    const float* W_in   = (const float*)d_in[1];
    const float* conv_w = (const float*)d_in[2];
    const float* conv_b = (const float*)d_in[3];
    const float* W_x    = (const float*)d_in[4];
    const float* W_dt   = (const float*)d_in[5];
    const float* b_dt   = (const float*)d_in[6];
    const float* A_log  = (const float*)d_in[7];
    const float* Dp     = (const float*)d_in[8];
    const float* W_out1 = (const float*)d_in[9];
    const float* W_out2 = (const float*)d_in[10];
    float* out = (float*)d_out;
    float* ws  = (float*)d_ws;

    // fp32 region (169.5 MB)
    float* xz   = ws;                    // 16777216
    float* u    = xz   + 16777216;       //  8388608
    float* xdbl = u    + 8388608;        //   393216
    float* dtb  = xdbl + 393216;         //  8388608 (delta)
    float* ysc  = dtb  + 8388608;        //  8388608
    float* Aneg = ysc  + 8388608;        //    32768
    float* S    = Aneg + 32768;          //     4096
    // bf16 tail (50.4 MB)
    __bf16* ycat16 = (__bf16*)(S + 4096);          // 16777216 el
    __bf16* h16    = ycat16 + 16777216;            //  8388608 el
    // overlays (regions dead at time of use)
    __bf16* W_in16  = (__bf16*)u;                  // before conv writes u
    __bf16* xb16    = W_in16 + 4194304;
    __bf16* Wout116 = (__bf16*)dtb;                // after scan reads dtb
    __bf16* Wout216 = Wout116 + 8388608;
    // scan summaries overlay ycat16's space (12 MB < 33.5 MB; ycat written later)
    float* chA    = (float*)ycat16;                // 4096*16*16 = 1048576
    float* chS    = chA + 1048576;                 // 1048576
    float* sinitb = chS + 1048576;                 // 1048576

    hipMemsetAsync(xdbl, 0, 393216 * sizeof(float), stream);
    hipMemsetAsync(S, 0, 4096 * sizeof(float), stream);
    aneg_k<<<128, 256, 0, stream>>>(A_log, Aneg);

    // bf16 conversions for input GEMM
    cvt_bf16_k<<<2048, 256, 0, stream>>>(W_in, W_in16, 524288);
    cvt_bf16_k<<<2048, 256, 0, stream>>>(x, xb16, 524288);

    // xz[b,e,l] = sum_d W_in[e,d] * x[b,l,d]   (M=4096, N=2048, K=1024)
    gemm_bf16_k<0, 0><<<dim3(16, 32, BATCH), 256, 0, stream>>>(
        W_in16, xb16, xz, D_MODEL, D_MODEL, D_MODEL, SEQLEN,
        (long long)SEQLEN * D_MODEL, (long long)4096 * SEQLEN);

    conv_silu_k<<<(BATCH * D_INNER * SEQLEN) / 256, 256, 0, stream>>>(xz, conv_w, conv_b, u);

    xdbl_k<<<dim3(SEQLEN / 64, 8, BATCH), 256, 0, stream>>>(u, W_x, xdbl);

    // dt[b,d,l] = sum_r W_dt[d,r] * x_dbl[b,l,r]   (small K=64, fp32)
    gemm_nt_k<0><<<dim3(SEQLEN / 64, D_INNER / 64, BATCH), 256, 0, stream>>>(
        W_dt, xdbl, dtb, D_INNER, SEQLEN, DT_RANK, DT_RANK, NPROJ, SEQLEN,
        0LL, (long long)SEQLEN * NPROJ, (long long)D_INNER * SEQLEN);

    softplus_k<<<(BATCH * D_INNER * SEQLEN) / 256, 256, 0, stream>>>(dtb, b_dt);

    // chunked scan: 16x time-parallel
    scan_p1_k<<<(BATCH * D_INNER * NCHUNK) / 4, 64, 0, stream>>>(dtb, u, xdbl, Aneg, chA, chS);
    scan_comb_k<<<256, 256, 0, stream>>>(chA, chS, sinitb);
    scan_p3_k<<<(BATCH * D_INNER * NCHUNK) / 4, 64, 0, stream>>>(dtb, u, xdbl, Aneg, sinitb, ysc);

    // weight conversions for output GEMMs (dtb region dead now)
    cvt_bf16_k<<<4096, 256, 0, stream>>>(W_out1, Wout116, 1048576);
    cvt_bf16_k<<<1024, 256, 0, stream>>>(W_out2, Wout216, 262144);

    ssum_k<<<dim3((BATCH * SEQLEN) / 256, 8), 256, 0, stream>>>(u, Dp, S);

    ytrans_k<<<dim3(SEQLEN / 32, D_INNER / 32, BATCH), dim3(32, 8), 0, stream>>>(ysc, u, xz, Dp, ycat16);

    yt_k<<<dim3(SEQLEN / 32, D_INNER / 64, BATCH), 256, 0, stream>>>(xdbl, Aneg, S, ycat16);

    // h = relu(ycat @ W_out1^T) -> bf16   (M=4096, N=2048, K=4096)
    gemm_bf16_k<1, 1><<<dim3(16, 32, 1), 256, 0, stream>>>(
        ycat16, Wout116, h16, 2 * D_INNER, 2 * D_INNER, 2 * D_INNER, D_INNER, 0LL, 0LL);

    // out = h @ W_out2^T   (M=4096, N=1024, K=2048)
    gemm_bf16_k<0, 0><<<dim3(8, 32, 1), 256, 0, stream>>>(
        h16, Wout216, out, D_INNER, D_INNER, D_INNER, D_MODEL, 0LL, 0LL);
}

// Round 12
// 669.558 us; speedup vs baseline: 1.2328x; 1.2328x over previous
//
#include <hip/hip_runtime.h>
#include <hip/hip_bf16.h>
#include <math.h>

#define D_MODEL 1024
#define D_STATE 16
#define D_INNER 2048
#define DT_RANK 64
#define BATCH   2
#define SEQLEN  2048
#define NPROJ   96   // DT_RANK + 2*D_STATE
#define NCHUNK  16
#define CHUNK   128  // SEQLEN / NCHUNK
#define KSPLIT  8

typedef __attribute__((ext_vector_type(8))) __bf16 bf16x8;
typedef __attribute__((ext_vector_type(4))) float f32x4;

__device__ __forceinline__ float silu_f(float x) { return x / (1.f + __expf(-x)); }

__device__ __forceinline__ void gload_lds16(const void* g, void* l) {
    __builtin_amdgcn_global_load_lds((const __attribute__((address_space(1))) void*)g,
                                     (__attribute__((address_space(3))) void*)l, 16, 0, 0);
}

// ---------------- bf16 MFMA NT GEMM: C[m,n] = sum_k A[m,k]*B[n,k] -------------
template<int RELU, int OUT_BF16>
__global__ __launch_bounds__(256) void gemm_bf16_k(
    const __bf16* __restrict__ A, const __bf16* __restrict__ B, void* __restrict__ Cv,
    int K, int lda, int ldb, int ldc, long long sB, long long sC)
{
    __shared__ alignas(16) __bf16 As[128 * 32];
    __shared__ alignas(16) __bf16 Bs[128 * 32];
    const int bz = blockIdx.z;
    B += (long long)bz * sB;
    const int m0 = blockIdx.y * 128, n0 = blockIdx.x * 128;
    const int tid = threadIdx.x;
    const int lane = tid & 63;
    const int wv = tid >> 6;
    const int wr = wv >> 1, wc = wv & 1;

    f32x4 acc[4][4];
    #pragma unroll
    for (int i = 0; i < 4; ++i)
        #pragma unroll
        for (int j = 0; j < 4; ++j) acc[i][j] = (f32x4){0.f, 0.f, 0.f, 0.f};

    const int ko = (lane >> 4) * 8;
    const int fr = lane & 15;

    for (int k0 = 0; k0 < K; k0 += 32) {
        #pragma unroll
        for (int q = 0; q < 2; ++q) {
            int f = tid + q * 256;
            int row = f >> 2, c16 = f & 3;
            gload_lds16(A + (long long)(m0 + row) * lda + k0 + c16 * 8, As + f * 8);
            gload_lds16(B + (long long)(n0 + row) * ldb + k0 + c16 * 8, Bs + f * 8);
        }
        __syncthreads();
        bf16x8 a[4], b[4];
        #pragma unroll
        for (int i = 0; i < 4; ++i) {
            a[i] = *(const bf16x8*)(As + (wr * 64 + i * 16 + fr) * 32 + ko);
            b[i] = *(const bf16x8*)(Bs + (wc * 64 + i * 16 + fr) * 32 + ko);
        }
        #pragma unroll
        for (int i = 0; i < 4; ++i)
            #pragma unroll
            for (int j = 0; j < 4; ++j)
                acc[i][j] = __builtin_amdgcn_mfma_f32_16x16x32_bf16(a[i], b[j], acc[i][j], 0, 0, 0);
        __syncthreads();
    }

    #pragma unroll
    for (int i = 0; i < 4; ++i) {
        const int row = m0 + wr * 64 + i * 16 + (lane >> 4) * 4;
        #pragma unroll
        for (int j = 0; j < 4; ++j) {
            const int col = n0 + wc * 64 + j * 16 + fr;
            #pragma unroll
            for (int r = 0; r < 4; ++r) {
                float v = acc[i][j][r];
                if (RELU) v = fmaxf(v, 0.f);
                if (OUT_BF16)
                    ((__bf16*)Cv)[(long long)bz * sC + (long long)(row + r) * ldc + col] = (__bf16)v;
                else
                    ((float*)Cv)[(long long)bz * sC + (long long)(row + r) * ldc + col] = v;
            }
        }
    }
}

// ---------------- f32 -> bf16 pack (8 per thread) ----------------
__global__ void cvt_bf16_k(const float* __restrict__ in, __bf16* __restrict__ out, int n8) {
    int i = blockIdx.x * 256 + threadIdx.x;
    if (i >= n8) return;
    const f32x4* p = (const f32x4*)in + (long long)i * 2;
    f32x4 v0 = p[0], v1 = p[1];
    bf16x8 o;
    o[0] = (__bf16)v0[0]; o[1] = (__bf16)v0[1]; o[2] = (__bf16)v0[2]; o[3] = (__bf16)v0[3];
    o[4] = (__bf16)v1[0]; o[5] = (__bf16)v1[1]; o[6] = (__bf16)v1[2]; o[7] = (__bf16)v1[3];
    ((bf16x8*)out)[i] = o;
}

// ---------------- generic fp32 NT GEMM (kept for small dt GEMM) ----------------
template<int RELU>
__global__ __launch_bounds__(256) void gemm_nt_k(
    const float* __restrict__ A, const float* __restrict__ B, float* __restrict__ C,
    int M, int N, int K, int lda, int ldb, int ldc,
    long long sA, long long sB, long long sC)
{
    __shared__ float As[16][68];
    __shared__ float Bs[16][68];
    const int bz = blockIdx.z;
    A += (long long)bz * sA; B += (long long)bz * sB; C += (long long)bz * sC;
    const int m0 = blockIdx.y * 64, n0 = blockIdx.x * 64;
    const int tid = threadIdx.x;
    const int lk = tid & 15, lr = tid >> 4;
    const int tx = tid & 15, ty = tid >> 4;
    float acc[4][4] = {};
    for (int k0 = 0; k0 < K; k0 += 16) {
        #pragma unroll
        for (int q = 0; q < 4; ++q) {
            int i = lr + q * 16;
            As[lk][i] = A[(long long)(m0 + i) * lda + k0 + lk];
            Bs[lk][i] = B[(long long)(n0 + i) * ldb + k0 + lk];
        }
        __syncthreads();
        #pragma unroll
        for (int k = 0; k < 16; ++k) {
            float a[4], b[4];
            #pragma unroll
            for (int j = 0; j < 4; ++j) { a[j] = As[k][ty*4+j]; b[j] = Bs[k][tx*4+j]; }
            #pragma unroll
            for (int i = 0; i < 4; ++i)
                #pragma unroll
                for (int j = 0; j < 4; ++j) acc[i][j] += a[i] * b[j];
        }
        __syncthreads();
    }
    #pragma unroll
    for (int i = 0; i < 4; ++i)
        #pragma unroll
        for (int j = 0; j < 4; ++j) {
            float v = acc[i][j];
            if (RELU) v = fmaxf(v, 0.f);
            C[(long long)(m0 + ty*4 + i) * ldc + n0 + tx*4 + j] = v;
        }
}

// ---------------- Aneg = -exp(A_log) ----------------
__global__ void aneg_k(const float* __restrict__ A_log, float* __restrict__ Aneg) {
    int i = blockIdx.x * 256 + threadIdx.x;
    if (i < D_INNER * D_STATE) Aneg[i] = -expf(A_log[i]);
}

// ---------------- depthwise causal conv(4) + bias + SiLU ----------------
__global__ void conv_silu_k(const float* __restrict__ xz, const float* __restrict__ cw,
                            const float* __restrict__ cb, float* __restrict__ u)
{
    int idx = blockIdx.x * 256 + threadIdx.x;
    int l = idx & (SEQLEN - 1);
    int d = (idx >> 11) & (D_INNER - 1);
    int b = idx >> 22;
    const float* xi = xz + ((long long)b * 2 * D_INNER + d) * SEQLEN;
    float acc = cb[d];
    #pragma unroll
    for (int k = 0; k < 4; ++k) {
        int t = l + k - 3;
        if (t >= 0) acc += xi[t] * cw[d * 4 + k];
    }
    u[idx] = silu_f(acc);
}

// ---------------- x_dbl partials: no atomics; coalesced per-split stores ------
// grid (32 l-tiles, KSPLIT, B). Per block: 64l x 96e partial over 256 k.
__global__ __launch_bounds__(256) void xdbl_k(const float* __restrict__ u,
    const float* __restrict__ Wx, float* __restrict__ xpart)
{
    __shared__ float Us[32][65];
    __shared__ float Ws[32][97];
    __shared__ float Os[64][97];
    const int b = blockIdx.z;
    const int l0 = blockIdx.x * 64;
    const int kbase = blockIdx.y * 256;
    const int tid = threadIdx.x;
    const int lx = tid & 63, eg = tid >> 6;
    const int ukk = tid >> 4;          // 0..15 (+16 for q=1)
    const int ul4 = tid & 15;
    const int we = tid >> 3;           // 0..31 (+32q)
    const int wj = tid & 7;

    float acc[24] = {};
    float4 ru0, ru1, rw0, rw1, rw2;

    {
        const int k0 = kbase;
        ru0 = ((const float4*)(u + ((long long)(b * D_INNER + k0 + ukk)) * SEQLEN + l0))[ul4];
        ru1 = ((const float4*)(u + ((long long)(b * D_INNER + k0 + ukk + 16)) * SEQLEN + l0))[ul4];
        rw0 = ((const float4*)(Wx + (long long)(we) * D_INNER + k0))[wj];
        rw1 = ((const float4*)(Wx + (long long)(we + 32) * D_INNER + k0))[wj];
        rw2 = ((const float4*)(Wx + (long long)(we + 64) * D_INNER + k0))[wj];
    }

    for (int kc = 0; kc < 8; ++kc) {
        Us[ukk][ul4*4+0] = ru0.x; Us[ukk][ul4*4+1] = ru0.y;
        Us[ukk][ul4*4+2] = ru0.z; Us[ukk][ul4*4+3] = ru0.w;
        Us[ukk+16][ul4*4+0] = ru1.x; Us[ukk+16][ul4*4+1] = ru1.y;
        Us[ukk+16][ul4*4+2] = ru1.z; Us[ukk+16][ul4*4+3] = ru1.w;
        Ws[wj*4+0][we] = rw0.x; Ws[wj*4+1][we] = rw0.y;
        Ws[wj*4+2][we] = rw0.z; Ws[wj*4+3][we] = rw0.w;
        Ws[wj*4+0][we+32] = rw1.x; Ws[wj*4+1][we+32] = rw1.y;
        Ws[wj*4+2][we+32] = rw1.z; Ws[wj*4+3][we+32] = rw1.w;
        Ws[wj*4+0][we+64] = rw2.x; Ws[wj*4+1][we+64] = rw2.y;
        Ws[wj*4+2][we+64] = rw2.z; Ws[wj*4+3][we+64] = rw2.w;
        __syncthreads();
        if (kc + 1 < 8) {
            const int kn = kbase + (kc + 1) * 32;
            ru0 = ((const float4*)(u + ((long long)(b * D_INNER + kn + ukk)) * SEQLEN + l0))[ul4];
            ru1 = ((const float4*)(u + ((long long)(b * D_INNER + kn + ukk + 16)) * SEQLEN + l0))[ul4];
            rw0 = ((const float4*)(Wx + (long long)(we) * D_INNER + kn))[wj];
            rw1 = ((const float4*)(Wx + (long long)(we + 32) * D_INNER + kn))[wj];
            rw2 = ((const float4*)(Wx + (long long)(we + 64) * D_INNER + kn))[wj];
        }
        #pragma unroll
        for (int kk = 0; kk < 32; ++kk) {
            float a = Us[kk][lx];
            #pragma unroll
            for (int j = 0; j < 24; ++j) acc[j] += a * Ws[kk][eg * 24 + j];
        }
        __syncthreads();
    }
    // LDS transpose (padded 97: conflict-free) then coalesced contiguous store
    #pragma unroll
    for (int j = 0; j < 24; ++j) Os[lx][eg * 24 + j] = acc[j];
    __syncthreads();
    float* xp = xpart + (((long long)blockIdx.y * BATCH + b) * SEQLEN + l0) * NPROJ;
    #pragma unroll
    for (int f = tid; f < 64 * NPROJ; f += 256)
        xp[f] = Os[f / NPROJ][f % NPROJ];
}

// ---------------- reduce KSPLIT partials -> xdbl ----------------
__global__ void xdbl_red_k(const float* __restrict__ xpart, float* __restrict__ xdbl) {
    int i = blockIdx.x * 256 + threadIdx.x;    // over 98304 float4s
    const float4* p = (const float4*)xpart;
    float4 s = p[i];
    #pragma unroll
    for (int ks = 1; ks < KSPLIT; ++ks) {
        float4 v = p[(long long)ks * (BATCH * SEQLEN * NPROJ / 4) + i];
        s.x += v.x; s.y += v.y; s.z += v.z; s.w += v.w;
    }
    ((float4*)xdbl)[i] = s;
}

// ---------------- delta = softplus(dt + b_dt) in place ----------------
__global__ void softplus_k(float* __restrict__ dtb, const float* __restrict__ b_dt) {
    int idx = blockIdx.x * 256 + threadIdx.x;
    int d = (idx >> 11) & (D_INNER - 1);
    float v = dtb[idx] + b_dt[d];
    dtb[idx] = fmaxf(v, 0.f) + log1pf(expf(-fabsf(v)));
}

// ======== chunked selective scan: time-parallel via associative combine =======
__global__ __launch_bounds__(64, 1) void scan_p1_k(const float* __restrict__ delta,
    const float* __restrict__ u, const float* __restrict__ xdbl,
    const float* __restrict__ Aneg, float* __restrict__ chA, float* __restrict__ chS)
{
    const int q = threadIdx.x >> 4;
    const int n = threadIdx.x & 15;
    const int gg = blockIdx.x * 4 + q;
    const int g = gg >> 4, c = gg & (NCHUNK - 1);
    const int b = g >> 11, d = g & (D_INNER - 1);
    const float a = Aneg[d * D_STATE + n];
    const long long base = (long long)g * SEQLEN + c * CHUNK;
    const float4* dv = (const float4*)(delta + base);
    const float4* uv = (const float4*)(u + base);
    const float* xb = xdbl + ((long long)b * SEQLEN + c * CHUNK) * NPROJ + DT_RANK + n;

    float4 pd[4], pu[4];
    float pB[16];
    #pragma unroll
    for (int i = 0; i < 4; ++i) { pd[i] = dv[i]; pu[i] = uv[i]; }
    #pragma unroll
    for (int i = 0; i < 16; ++i) pB[i] = xb[i * NPROJ];

    float s = 0.f, ap = 1.f;
    for (int t0 = 0; t0 < CHUNK; t0 += 16) {
        float cd[16], cu[16], cB[16];
        #pragma unroll
        for (int i = 0; i < 4; ++i) {
            cd[4*i] = pd[i].x; cd[4*i+1] = pd[i].y; cd[4*i+2] = pd[i].z; cd[4*i+3] = pd[i].w;
            cu[4*i] = pu[i].x; cu[4*i+1] = pu[i].y; cu[4*i+2] = pu[i].z; cu[4*i+3] = pu[i].w;
        }
        #pragma unroll
        for (int i = 0; i < 16; ++i) cB[i] = pB[i];
        if (t0 + 16 < CHUNK) {
            const int nb = (t0 >> 2) + 4;
            #pragma unroll
            for (int i = 0; i < 4; ++i) { pd[i] = dv[nb + i]; pu[i] = uv[nb + i]; }
            const float* xn = xb + (t0 + 16) * NPROJ;
            #pragma unroll
            for (int i = 0; i < 16; ++i) pB[i] = xn[i * NPROJ];
        }
        float dA[16], wB[16];
        #pragma unroll
        for (int i = 0; i < 16; ++i) {
            dA[i] = __expf(cd[i] * a);
            wB[i] = cd[i] * cu[i] * cB[i];
        }
        #pragma unroll
        for (int i = 0; i < 16; ++i) {
            s = dA[i] * s + wB[i];
            ap *= dA[i];
        }
    }
    chA[(long long)gg * 16 + n] = ap;
    chS[(long long)gg * 16 + n] = s;
}

__global__ void scan_comb_k(const float* __restrict__ chA, const float* __restrict__ chS,
                            float* __restrict__ sinit)
{
    int idx = blockIdx.x * 256 + threadIdx.x;      // (g, n), 65536 total
    int g = idx >> 4, n = idx & 15;
    const float* A = chA + (long long)g * (NCHUNK * 16) + n;
    const float* S = chS + (long long)g * (NCHUNK * 16) + n;
    float av[NCHUNK], sv[NCHUNK];
    #pragma unroll
    for (int c = 0; c < NCHUNK; ++c) { av[c] = A[c * 16]; sv[c] = S[c * 16]; }
    float* si = sinit + (long long)g * (NCHUNK * 16) + n;
    float carry = 0.f;
    #pragma unroll
    for (int c = 0; c < NCHUNK; ++c) {
        si[c * 16] = carry;
        carry = sv[c] + av[c] * carry;
    }
}

__global__ __launch_bounds__(64, 1) void scan_p3_k(const float* __restrict__ delta,
    const float* __restrict__ u, const float* __restrict__ xdbl,
    const float* __restrict__ Aneg, const float* __restrict__ sinit, float* __restrict__ y)
{
    __shared__ float lp[4][16][17];
    const int q = threadIdx.x >> 4;
    const int n = threadIdx.x & 15;
    const int gg = blockIdx.x * 4 + q;
    const int g = gg >> 4, c = gg & (NCHUNK - 1);
    const int b = g >> 11, d = g & (D_INNER - 1);
    const float a = Aneg[d * D_STATE + n];
    const long long base = (long long)g * SEQLEN + c * CHUNK;
    const float4* dv = (const float4*)(delta + base);
    const float4* uv = (const float4*)(u + base);
    const float* xb = xdbl + ((long long)b * SEQLEN + c * CHUNK) * NPROJ + DT_RANK + n;
    float* yl = y + base;

    float4 pd[4], pu[4];
    float pB[16], pC[16];
    #pragma unroll
    for (int i = 0; i < 4; ++i) { pd[i] = dv[i]; pu[i] = uv[i]; }
    #pragma unroll
    for (int i = 0; i < 16; ++i) { pB[i] = xb[i * NPROJ]; pC[i] = xb[i * NPROJ + D_STATE]; }

    float s = sinit[(long long)gg * 16 + n];
    for (int t0 = 0; t0 < CHUNK; t0 += 16) {
        float cd[16], cu[16], cB[16], cC[16];
        #pragma unroll
        for (int i = 0; i < 4; ++i) {
            cd[4*i] = pd[i].x; cd[4*i+1] = pd[i].y; cd[4*i+2] = pd[i].z; cd[4*i+3] = pd[i].w;
            cu[4*i] = pu[i].x; cu[4*i+1] = pu[i].y; cu[4*i+2] = pu[i].z; cu[4*i+3] = pu[i].w;
        }
        #pragma unroll
        for (int i = 0; i < 16; ++i) { cB[i] = pB[i]; cC[i] = pC[i]; }
        if (t0 + 16 < CHUNK) {
            const int nb = (t0 >> 2) + 4;
            #pragma unroll
            for (int i = 0; i < 4; ++i) { pd[i] = dv[nb + i]; pu[i] = uv[nb + i]; }
            const float* xn = xb + (t0 + 16) * NPROJ;
            #pragma unroll
            for (int i = 0; i < 16; ++i) { pB[i] = xn[i * NPROJ]; pC[i] = xn[i * NPROJ + D_STATE]; }
        }
        float dA[16], wB[16];
        #pragma unroll
        for (int i = 0; i < 16; ++i) {
            dA[i] = __expf(cd[i] * a);
            wB[i] = cd[i] * cu[i] * cB[i];
        }
        #pragma unroll
        for (int i = 0; i < 16; ++i) {
            s = dA[i] * s + wB[i];
            lp[q][n][i] = s * cC[i];
        }
        __syncthreads();
        float v[16];
        #pragma unroll
        for (int j = 0; j < 16; ++j) v[j] = lp[q][j][n];
        float acc = 0.f;
        #pragma unroll
        for (int j = 0; j < 16; ++j) acc += v[j];
        yl[t0 + n] = acc;
        __syncthreads();
    }
}

// ---------------- S[b,l] = sum_d Dp[d]*u[b,d,l] ----------------
__global__ void ssum_k(const float* __restrict__ u, const float* __restrict__ Dp,
                       float* __restrict__ S)
{
    int li = blockIdx.x * 256 + threadIdx.x;
    int c = blockIdx.y;
    int b = li >> 11, l = li & (SEQLEN - 1);
    const float* up = u + (long long)b * D_INNER * SEQLEN + l;
    float acc = 0.f;
    for (int d = c * 256; d < c * 256 + 256; ++d)
        acc += Dp[d] * up[(long long)d * SEQLEN];
    atomicAdd(&S[li], acc);
}

// ---------------- y=(y+Dp*u)*silu(z), transposed into ycat16[...,:2048] -------
__global__ __launch_bounds__(256) void ytrans_k(const float* __restrict__ ysc,
    const float* __restrict__ u, const float* __restrict__ xz,
    const float* __restrict__ Dp, __bf16* __restrict__ ycat)
{
    __shared__ float tile[32][33];
    const int b = blockIdx.z;
    const int d0 = blockIdx.y * 32, l0 = blockIdx.x * 32;
    const int lx = threadIdx.x, dy = threadIdx.y;
    #pragma unroll
    for (int j = 0; j < 4; ++j) {
        int d = d0 + dy + j * 8;
        long long i  = ((long long)b * D_INNER + d) * SEQLEN + l0 + lx;
        long long iz = ((long long)b * 2 * D_INNER + D_INNER + d) * SEQLEN + l0 + lx;
        tile[dy + j * 8][lx] = (ysc[i] + Dp[d] * u[i]) * silu_f(xz[iz]);
    }
    __syncthreads();
    #pragma unroll
    for (int j = 0; j < 4; ++j) {
        int l = l0 + dy + j * 8;
        ycat[((long long)b * SEQLEN + l) * (2 * D_INNER) + d0 + lx] = (__bf16)tile[lx][dy + j * 8];
    }
}

// ---------------- y_t -> ycat16[...,2048:] ----------------
__global__ __launch_bounds__(256) void yt_k(const float* __restrict__ xdbl,
    const float* __restrict__ Aneg, const float* __restrict__ S, __bf16* __restrict__ ycat)
{
    __shared__ float Cs[16][33];
    __shared__ float An[16][64];
    __shared__ float Sv[32];
    const int b = blockIdx.z;
    const int d0 = blockIdx.y * 64, l0 = blockIdx.x * 32;
    const int tid = threadIdx.x;
    for (int f = tid; f < 512; f += 256) {
        int n = f & 15, l = f >> 4;
        Cs[n][l] = xdbl[((long long)b * SEQLEN + l0 + l) * NPROJ + DT_RANK + D_STATE + n];
    }
    for (int f = tid; f < 1024; f += 256) {
        int n = f & 15, d = f >> 4;
        An[n][d] = Aneg[(d0 + d) * D_STATE + n];
    }
    if (tid < 32) Sv[tid] = S[b * SEQLEN + l0 + tid];
    __syncthreads();
    const int dx = tid & 63, lg = tid >> 6;
    #pragma unroll
    for (int j = 0; j < 8; ++j) {
        int l = lg * 8 + j;
        float acc = Sv[l];
        #pragma unroll
        for (int n = 0; n < 16; ++n) acc += Cs[n][l] * An[n][dx];
        ycat[((long long)b * SEQLEN + l0 + l) * (2 * D_INNER) + D_INNER + d0 + dx] = (__bf16)acc;
    }
}

extern "C" void kernel_launch(void* const* d_in, const int* in_sizes, int n_in,
                              void* d_out, int out_size, void* d_ws, size_t ws_size,
                              hipStream_t stream)
{
    const float* x      = (const float*)d_in[0];
    const float* W_in   = (const float*)d_in[1];
    const float* conv_w = (const float*)d_in[2];
    const float* conv_b = (const float*)d_in[3];
    const float* W_x    = (const float*)d_in[4];
    const float* W_dt   = (const float*)d_in[5];
    const float* b_dt   = (const float*)d_in[6];
    const float* A_log  = (const float*)d_in[7];
    const float* Dp     = (const float*)d_in[8];
    const float* W_out1 = (const float*)d_in[9];
    const float* W_out2 = (const float*)d_in[10];
    float* out = (float*)d_out;
    float* ws  = (float*)d_ws;

    // fp32 region (169.5 MB)
    float* xz   = ws;                    // 16777216
    float* u    = xz   + 16777216;       //  8388608
    float* xdbl = u    + 8388608;        //   393216
    float* dtb  = xdbl + 393216;         //  8388608 (delta)
    float* ysc  = dtb  + 8388608;        //  8388608
    float* Aneg = ysc  + 8388608;        //    32768
    float* S    = Aneg + 32768;          //     4096
    // bf16 tail (50.4 MB)
    __bf16* ycat16 = (__bf16*)(S + 4096);          // 16777216 el
    __bf16* h16    = ycat16 + 16777216;            //  8388608 el
    // overlays (regions dead at time of use)
    __bf16* W_in16  = (__bf16*)u;                  // before conv writes u
    __bf16* xb16    = W_in16 + 4194304;
    __bf16* Wout116 = (__bf16*)dtb;                // after scan reads dtb
    __bf16* Wout216 = Wout116 + 8388608;
    // scan summaries overlay ycat16's space (12 MB < 33.5 MB; ycat written later)
    float* chA    = (float*)ycat16;                // 4096*16*16 = 1048576
    float* chS    = chA + 1048576;                 // 1048576
    float* sinitb = chS + 1048576;                 // 1048576
    // xdbl partials overlay h16's space (12.6 MB < 16.8 MB; h16 written later)
    float* xpart  = (float*)h16;                   // 8*2*2048*96 = 3145728

    hipMemsetAsync(S, 0, 4096 * sizeof(float), stream);
    aneg_k<<<128, 256, 0, stream>>>(A_log, Aneg);

    // bf16 conversions for input GEMM
    cvt_bf16_k<<<2048, 256, 0, stream>>>(W_in, W_in16, 524288);
    cvt_bf16_k<<<2048, 256, 0, stream>>>(x, xb16, 524288);

    // xz[b,e,l] = sum_d W_in[e,d] * x[b,l,d]   (M=4096, N=2048, K=1024)
    gemm_bf16_k<0, 0><<<dim3(16, 32, BATCH), 256, 0, stream>>>(
        W_in16, xb16, xz, D_MODEL, D_MODEL, D_MODEL, SEQLEN,
        (long long)SEQLEN * D_MODEL, (long long)4096 * SEQLEN);

    conv_silu_k<<<(BATCH * D_INNER * SEQLEN) / 256, 256, 0, stream>>>(xz, conv_w, conv_b, u);

    xdbl_k<<<dim3(SEQLEN / 64, KSPLIT, BATCH), 256, 0, stream>>>(u, W_x, xpart);
    xdbl_red_k<<<(BATCH * SEQLEN * NPROJ / 4) / 256, 256, 0, stream>>>(xpart, xdbl);

    // dt[b,d,l] = sum_r W_dt[d,r] * x_dbl[b,l,r]   (small K=64, fp32)
    gemm_nt_k<0><<<dim3(SEQLEN / 64, D_INNER / 64, BATCH), 256, 0, stream>>>(
        W_dt, xdbl, dtb, D_INNER, SEQLEN, DT_RANK, DT_RANK, NPROJ, SEQLEN,
        0LL, (long long)SEQLEN * NPROJ, (long long)D_INNER * SEQLEN);

    softplus_k<<<(BATCH * D_INNER * SEQLEN) / 256, 256, 0, stream>>>(dtb, b_dt);

    // chunked scan: 16x time-parallel
    scan_p1_k<<<(BATCH * D_INNER * NCHUNK) / 4, 64, 0, stream>>>(dtb, u, xdbl, Aneg, chA, chS);
    scan_comb_k<<<256, 256, 0, stream>>>(chA, chS, sinitb);
    scan_p3_k<<<(BATCH * D_INNER * NCHUNK) / 4, 64, 0, stream>>>(dtb, u, xdbl, Aneg, sinitb, ysc);

    // weight conversions for output GEMMs (dtb region dead now)
    cvt_bf16_k<<<4096, 256, 0, stream>>>(W_out1, Wout116, 1048576);
    cvt_bf16_k<<<1024, 256, 0, stream>>>(W_out2, Wout216, 262144);

    ssum_k<<<dim3((BATCH * SEQLEN) / 256, 8), 256, 0, stream>>>(u, Dp, S);

    ytrans_k<<<dim3(SEQLEN / 32, D_INNER / 32, BATCH), dim3(32, 8), 0, stream>>>(ysc, u, xz, Dp, ycat16);

    yt_k<<<dim3(SEQLEN / 32, D_INNER / 64, BATCH), 256, 0, stream>>>(xdbl, Aneg, S, ycat16);

    // h = relu(ycat @ W_out1^T) -> bf16   (M=4096, N=2048, K=4096)
    gemm_bf16_k<1, 1><<<dim3(16, 32, 1), 256, 0, stream>>>(
        ycat16, Wout116, h16, 2 * D_INNER, 2 * D_INNER, 2 * D_INNER, D_INNER, 0LL, 0LL);

    // out = h @ W_out2^T   (M=4096, N=1024, K=2048)
    gemm_bf16_k<0, 0><<<dim3(8, 32, 1), 256, 0, stream>>>(
        h16, Wout216, out, D_INNER, D_INNER, D_INNER, D_MODEL, 0LL, 0LL);
}

// Round 13
// 589.350 us; speedup vs baseline: 1.4005x; 1.1361x over previous
//
#include <hip/hip_runtime.h>
#include <hip/hip_bf16.h>
#include <math.h>

#define D_MODEL 1024
#define D_STATE 16
#define D_INNER 2048
#define DT_RANK 64
#define BATCH   2
#define SEQLEN  2048
#define NPROJ   96   // DT_RANK + 2*D_STATE (logical)
#define XSTR    128  // padded x_dbl row stride
#define NCHUNK  16
#define CHUNK   128  // SEQLEN / NCHUNK

typedef __attribute__((ext_vector_type(8))) __bf16 bf16x8;
typedef __attribute__((ext_vector_type(4))) float f32x4;

__device__ __forceinline__ float silu_f(float x) { return x / (1.f + __expf(-x)); }

__device__ __forceinline__ void gload_lds16(const void* g, void* l) {
    __builtin_amdgcn_global_load_lds((const __attribute__((address_space(1))) void*)g,
                                     (__attribute__((address_space(3))) void*)l, 16, 0, 0);
}

// ---------------- bf16 MFMA NT GEMM: C[m,n] = sum_k A[m,k]*B[n,k] -------------
template<int RELU, int OUT_BF16>
__global__ __launch_bounds__(256) void gemm_bf16_k(
    const __bf16* __restrict__ A, const __bf16* __restrict__ B, void* __restrict__ Cv,
    int K, int lda, int ldb, int ldc, long long sB, long long sC)
{
    __shared__ alignas(16) __bf16 As[128 * 32];
    __shared__ alignas(16) __bf16 Bs[128 * 32];
    const int bz = blockIdx.z;
    B += (long long)bz * sB;
    const int m0 = blockIdx.y * 128, n0 = blockIdx.x * 128;
    const int tid = threadIdx.x;
    const int lane = tid & 63;
    const int wv = tid >> 6;
    const int wr = wv >> 1, wc = wv & 1;

    f32x4 acc[4][4];
    #pragma unroll
    for (int i = 0; i < 4; ++i)
        #pragma unroll
        for (int j = 0; j < 4; ++j) acc[i][j] = (f32x4){0.f, 0.f, 0.f, 0.f};

    const int ko = (lane >> 4) * 8;
    const int fr = lane & 15;

    for (int k0 = 0; k0 < K; k0 += 32) {
        #pragma unroll
        for (int q = 0; q < 2; ++q) {
            int f = tid + q * 256;
            int row = f >> 2, c16 = f & 3;
            gload_lds16(A + (long long)(m0 + row) * lda + k0 + c16 * 8, As + f * 8);
            gload_lds16(B + (long long)(n0 + row) * ldb + k0 + c16 * 8, Bs + f * 8);
        }
        __syncthreads();
        bf16x8 a[4], b[4];
        #pragma unroll
        for (int i = 0; i < 4; ++i) {
            a[i] = *(const bf16x8*)(As + (wr * 64 + i * 16 + fr) * 32 + ko);
            b[i] = *(const bf16x8*)(Bs + (wc * 64 + i * 16 + fr) * 32 + ko);
        }
        #pragma unroll
        for (int i = 0; i < 4; ++i)
            #pragma unroll
            for (int j = 0; j < 4; ++j)
                acc[i][j] = __builtin_amdgcn_mfma_f32_16x16x32_bf16(a[i], b[j], acc[i][j], 0, 0, 0);
        __syncthreads();
    }

    #pragma unroll
    for (int i = 0; i < 4; ++i) {
        const int row = m0 + wr * 64 + i * 16 + (lane >> 4) * 4;
        #pragma unroll
        for (int j = 0; j < 4; ++j) {
            const int col = n0 + wc * 64 + j * 16 + fr;
            #pragma unroll
            for (int r = 0; r < 4; ++r) {
                float v = acc[i][j][r];
                if (RELU) v = fmaxf(v, 0.f);
                if (OUT_BF16)
                    ((__bf16*)Cv)[(long long)bz * sC + (long long)(row + r) * ldc + col] = (__bf16)v;
                else
                    ((float*)Cv)[(long long)bz * sC + (long long)(row + r) * ldc + col] = v;
            }
        }
    }
}

// ---------------- f32 -> bf16 pack (8 per thread) ----------------
__global__ void cvt_bf16_k(const float* __restrict__ in, __bf16* __restrict__ out, int n8) {
    int i = blockIdx.x * 256 + threadIdx.x;
    if (i >= n8) return;
    const f32x4* p = (const f32x4*)in + (long long)i * 2;
    f32x4 v0 = p[0], v1 = p[1];
    bf16x8 o;
    o[0] = (__bf16)v0[0]; o[1] = (__bf16)v0[1]; o[2] = (__bf16)v0[2]; o[3] = (__bf16)v0[3];
    o[4] = (__bf16)v1[0]; o[5] = (__bf16)v1[1]; o[6] = (__bf16)v1[2]; o[7] = (__bf16)v1[3];
    ((bf16x8*)out)[i] = o;
}

// ---------------- generic fp32 NT GEMM (kept for small dt GEMM) ----------------
template<int RELU>
__global__ __launch_bounds__(256) void gemm_nt_k(
    const float* __restrict__ A, const float* __restrict__ B, float* __restrict__ C,
    int M, int N, int K, int lda, int ldb, int ldc,
    long long sA, long long sB, long long sC)
{
    __shared__ float As[16][68];
    __shared__ float Bs[16][68];
    const int bz = blockIdx.z;
    A += (long long)bz * sA; B += (long long)bz * sB; C += (long long)bz * sC;
    const int m0 = blockIdx.y * 64, n0 = blockIdx.x * 64;
    const int tid = threadIdx.x;
    const int lk = tid & 15, lr = tid >> 4;
    const int tx = tid & 15, ty = tid >> 4;
    float acc[4][4] = {};
    for (int k0 = 0; k0 < K; k0 += 16) {
        #pragma unroll
        for (int q = 0; q < 4; ++q) {
            int i = lr + q * 16;
            As[lk][i] = A[(long long)(m0 + i) * lda + k0 + lk];
            Bs[lk][i] = B[(long long)(n0 + i) * ldb + k0 + lk];
        }
        __syncthreads();
        #pragma unroll
        for (int k = 0; k < 16; ++k) {
            float a[4], b[4];
            #pragma unroll
            for (int j = 0; j < 4; ++j) { a[j] = As[k][ty*4+j]; b[j] = Bs[k][tx*4+j]; }
            #pragma unroll
            for (int i = 0; i < 4; ++i)
                #pragma unroll
                for (int j = 0; j < 4; ++j) acc[i][j] += a[i] * b[j];
        }
        __syncthreads();
    }
    #pragma unroll
    for (int i = 0; i < 4; ++i)
        #pragma unroll
        for (int j = 0; j < 4; ++j) {
            float v = acc[i][j];
            if (RELU) v = fmaxf(v, 0.f);
            C[(long long)(m0 + ty*4 + i) * ldc + n0 + tx*4 + j] = v;
        }
}

// ---------------- Aneg = -exp(A_log) ----------------
__global__ void aneg_k(const float* __restrict__ A_log, float* __restrict__ Aneg) {
    int i = blockIdx.x * 256 + threadIdx.x;
    if (i < D_INNER * D_STATE) Aneg[i] = -expf(A_log[i]);
}

// ---------------- depthwise causal conv(4) + bias + SiLU, dual-layout out -----
// Writes u[b,d,l] (fp32, scan/ssum/ytrans) and u_t[b,l,d] (bf16, MFMA GEMM).
__global__ __launch_bounds__(256) void conv_silu_k(const float* __restrict__ xz,
    const float* __restrict__ cw, const float* __restrict__ cb,
    float* __restrict__ u, __bf16* __restrict__ ut)
{
    __shared__ float tile[32][33];
    const int b = blockIdx.z;
    const int d0 = blockIdx.y * 32, l0 = blockIdx.x * 32;
    const int lx = threadIdx.x, dy = threadIdx.y;   // (32,8)
    #pragma unroll
    for (int j = 0; j < 4; ++j) {
        int d = d0 + dy + j * 8;
        const float* xi = xz + ((long long)b * 2 * D_INNER + d) * SEQLEN;
        int l = l0 + lx;
        float acc = cb[d];
        #pragma unroll
        for (int k = 0; k < 4; ++k) {
            int t = l + k - 3;
            if (t >= 0) acc += xi[t] * cw[d * 4 + k];
        }
        float v = silu_f(acc);
        u[((long long)b * D_INNER + d) * SEQLEN + l] = v;
        tile[dy + j * 8][lx] = v;
    }
    __syncthreads();
    #pragma unroll
    for (int j = 0; j < 4; ++j) {
        int l = l0 + dy + j * 8;
        ut[((long long)b * SEQLEN + l) * D_INNER + d0 + lx] = (__bf16)tile[lx][dy + j * 8];
    }
}

// ---------------- delta = softplus(dt + b_dt) in place ----------------
__global__ void softplus_k(float* __restrict__ dtb, const float* __restrict__ b_dt) {
    int idx = blockIdx.x * 256 + threadIdx.x;
    int d = (idx >> 11) & (D_INNER - 1);
    float v = dtb[idx] + b_dt[d];
    dtb[idx] = fmaxf(v, 0.f) + log1pf(expf(-fabsf(v)));
}

// ======== chunked selective scan: time-parallel via associative combine =======
__global__ __launch_bounds__(64, 1) void scan_p1_k(const float* __restrict__ delta,
    const float* __restrict__ u, const float* __restrict__ xdbl,
    const float* __restrict__ Aneg, float* __restrict__ chA, float* __restrict__ chS)
{
    const int q = threadIdx.x >> 4;
    const int n = threadIdx.x & 15;
    const int gg = blockIdx.x * 4 + q;
    const int g = gg >> 4, c = gg & (NCHUNK - 1);
    const int b = g >> 11, d = g & (D_INNER - 1);
    const float a = Aneg[d * D_STATE + n];
    const long long base = (long long)g * SEQLEN + c * CHUNK;
    const float4* dv = (const float4*)(delta + base);
    const float4* uv = (const float4*)(u + base);
    const float* xb = xdbl + ((long long)b * SEQLEN + c * CHUNK) * XSTR + DT_RANK + n;

    float4 pd[4], pu[4];
    float pB[16];
    #pragma unroll
    for (int i = 0; i < 4; ++i) { pd[i] = dv[i]; pu[i] = uv[i]; }
    #pragma unroll
    for (int i = 0; i < 16; ++i) pB[i] = xb[i * XSTR];

    float s = 0.f, ap = 1.f;
    for (int t0 = 0; t0 < CHUNK; t0 += 16) {
        float cd[16], cu[16], cB[16];
        #pragma unroll
        for (int i = 0; i < 4; ++i) {
            cd[4*i] = pd[i].x; cd[4*i+1] = pd[i].y; cd[4*i+2] = pd[i].z; cd[4*i+3] = pd[i].w;
            cu[4*i] = pu[i].x; cu[4*i+1] = pu[i].y; cu[4*i+2] = pu[i].z; cu[4*i+3] = pu[i].w;
        }
        #pragma unroll
        for (int i = 0; i < 16; ++i) cB[i] = pB[i];
        if (t0 + 16 < CHUNK) {
            const int nb = (t0 >> 2) + 4;
            #pragma unroll
            for (int i = 0; i < 4; ++i) { pd[i] = dv[nb + i]; pu[i] = uv[nb + i]; }
            const float* xn = xb + (t0 + 16) * XSTR;
            #pragma unroll
            for (int i = 0; i < 16; ++i) pB[i] = xn[i * XSTR];
        }
        float dA[16], wB[16];
        #pragma unroll
        for (int i = 0; i < 16; ++i) {
            dA[i] = __expf(cd[i] * a);
            wB[i] = cd[i] * cu[i] * cB[i];
        }
        #pragma unroll
        for (int i = 0; i < 16; ++i) {
            s = dA[i] * s + wB[i];
            ap *= dA[i];
        }
    }
    chA[(long long)gg * 16 + n] = ap;
    chS[(long long)gg * 16 + n] = s;
}

__global__ void scan_comb_k(const float* __restrict__ chA, const float* __restrict__ chS,
                            float* __restrict__ sinit)
{
    int idx = blockIdx.x * 256 + threadIdx.x;      // (g, n), 65536 total
    int g = idx >> 4, n = idx & 15;
    const float* A = chA + (long long)g * (NCHUNK * 16) + n;
    const float* S = chS + (long long)g * (NCHUNK * 16) + n;
    float av[NCHUNK], sv[NCHUNK];
    #pragma unroll
    for (int c = 0; c < NCHUNK; ++c) { av[c] = A[c * 16]; sv[c] = S[c * 16]; }
    float* si = sinit + (long long)g * (NCHUNK * 16) + n;
    float carry = 0.f;
    #pragma unroll
    for (int c = 0; c < NCHUNK; ++c) {
        si[c * 16] = carry;
        carry = sv[c] + av[c] * carry;
    }
}

__global__ __launch_bounds__(64, 1) void scan_p3_k(const float* __restrict__ delta,
    const float* __restrict__ u, const float* __restrict__ xdbl,
    const float* __restrict__ Aneg, const float* __restrict__ sinit, float* __restrict__ y)
{
    __shared__ float lp[4][16][17];
    const int q = threadIdx.x >> 4;
    const int n = threadIdx.x & 15;
    const int gg = blockIdx.x * 4 + q;
    const int g = gg >> 4, c = gg & (NCHUNK - 1);
    const int b = g >> 11, d = g & (D_INNER - 1);
    const float a = Aneg[d * D_STATE + n];
    const long long base = (long long)g * SEQLEN + c * CHUNK;
    const float4* dv = (const float4*)(delta + base);
    const float4* uv = (const float4*)(u + base);
    const float* xb = xdbl + ((long long)b * SEQLEN + c * CHUNK) * XSTR + DT_RANK + n;
    float* yl = y + base;

    float4 pd[4], pu[4];
    float pB[16], pC[16];
    #pragma unroll
    for (int i = 0; i < 4; ++i) { pd[i] = dv[i]; pu[i] = uv[i]; }
    #pragma unroll
    for (int i = 0; i < 16; ++i) { pB[i] = xb[i * XSTR]; pC[i] = xb[i * XSTR + D_STATE]; }

    float s = sinit[(long long)gg * 16 + n];
    for (int t0 = 0; t0 < CHUNK; t0 += 16) {
        float cd[16], cu[16], cB[16], cC[16];
        #pragma unroll
        for (int i = 0; i < 4; ++i) {
            cd[4*i] = pd[i].x; cd[4*i+1] = pd[i].y; cd[4*i+2] = pd[i].z; cd[4*i+3] = pd[i].w;
            cu[4*i] = pu[i].x; cu[4*i+1] = pu[i].y; cu[4*i+2] = pu[i].z; cu[4*i+3] = pu[i].w;
        }
        #pragma unroll
        for (int i = 0; i < 16; ++i) { cB[i] = pB[i]; cC[i] = pC[i]; }
        if (t0 + 16 < CHUNK) {
            const int nb = (t0 >> 2) + 4;
            #pragma unroll
            for (int i = 0; i < 4; ++i) { pd[i] = dv[nb + i]; pu[i] = uv[nb + i]; }
            const float* xn = xb + (t0 + 16) * XSTR;
            #pragma unroll
            for (int i = 0; i < 16; ++i) { pB[i] = xn[i * XSTR]; pC[i] = xn[i * XSTR + D_STATE]; }
        }
        float dA[16], wB[16];
        #pragma unroll
        for (int i = 0; i < 16; ++i) {
            dA[i] = __expf(cd[i] * a);
            wB[i] = cd[i] * cu[i] * cB[i];
        }
        #pragma unroll
        for (int i = 0; i < 16; ++i) {
            s = dA[i] * s + wB[i];
            lp[q][n][i] = s * cC[i];
        }
        __syncthreads();
        float v[16];
        #pragma unroll
        for (int j = 0; j < 16; ++j) v[j] = lp[q][j][n];
        float acc = 0.f;
        #pragma unroll
        for (int j = 0; j < 16; ++j) acc += v[j];
        yl[t0 + n] = acc;
        __syncthreads();
    }
}

// ---------------- S[b,l] = sum_d Dp[d]*u[b,d,l] ----------------
__global__ void ssum_k(const float* __restrict__ u, const float* __restrict__ Dp,
                       float* __restrict__ S)
{
    int li = blockIdx.x * 256 + threadIdx.x;
    int c = blockIdx.y;
    int b = li >> 11, l = li & (SEQLEN - 1);
    const float* up = u + (long long)b * D_INNER * SEQLEN + l;
    float acc = 0.f;
    for (int d = c * 256; d < c * 256 + 256; ++d)
        acc += Dp[d] * up[(long long)d * SEQLEN];
    atomicAdd(&S[li], acc);
}

// ---------------- y=(y+Dp*u)*silu(z), transposed into ycat16[...,:2048] -------
__global__ __launch_bounds__(256) void ytrans_k(const float* __restrict__ ysc,
    const float* __restrict__ u, const float* __restrict__ xz,
    const float* __restrict__ Dp, __bf16* __restrict__ ycat)
{
    __shared__ float tile[32][33];
    const int b = blockIdx.z;
    const int d0 = blockIdx.y * 32, l0 = blockIdx.x * 32;
    const int lx = threadIdx.x, dy = threadIdx.y;
    #pragma unroll
    for (int j = 0; j < 4; ++j) {
        int d = d0 + dy + j * 8;
        long long i  = ((long long)b * D_INNER + d) * SEQLEN + l0 + lx;
        long long iz = ((long long)b * 2 * D_INNER + D_INNER + d) * SEQLEN + l0 + lx;
        tile[dy + j * 8][lx] = (ysc[i] + Dp[d] * u[i]) * silu_f(xz[iz]);
    }
    __syncthreads();
    #pragma unroll
    for (int j = 0; j < 4; ++j) {
        int l = l0 + dy + j * 8;
        ycat[((long long)b * SEQLEN + l) * (2 * D_INNER) + d0 + lx] = (__bf16)tile[lx][dy + j * 8];
    }
}

// ---------------- y_t -> ycat16[...,2048:] ----------------
__global__ __launch_bounds__(256) void yt_k(const float* __restrict__ xdbl,
    const float* __restrict__ Aneg, const float* __restrict__ S, __bf16* __restrict__ ycat)
{
    __shared__ float Cs[16][33];
    __shared__ float An[16][64];
    __shared__ float Sv[32];
    const int b = blockIdx.z;
    const int d0 = blockIdx.y * 64, l0 = blockIdx.x * 32;
    const int tid = threadIdx.x;
    for (int f = tid; f < 512; f += 256) {
        int n = f & 15, l = f >> 4;
        Cs[n][l] = xdbl[((long long)b * SEQLEN + l0 + l) * XSTR + DT_RANK + D_STATE + n];
    }
    for (int f = tid; f < 1024; f += 256) {
        int n = f & 15, d = f >> 4;
        An[n][d] = Aneg[(d0 + d) * D_STATE + n];
    }
    if (tid < 32) Sv[tid] = S[b * SEQLEN + l0 + tid];
    __syncthreads();
    const int dx = tid & 63, lg = tid >> 6;
    #pragma unroll
    for (int j = 0; j < 8; ++j) {
        int l = lg * 8 + j;
        float acc = Sv[l];
        #pragma unroll
        for (int n = 0; n < 16; ++n) acc += Cs[n][l] * An[n][dx];
        ycat[((long long)b * SEQLEN + l0 + l) * (2 * D_INNER) + D_INNER + d0 + dx] = (__bf16)acc;
    }
}

extern "C" void kernel_launch(void* const* d_in, const int* in_sizes, int n_in,
                              void* d_out, int out_size, void* d_ws, size_t ws_size,
                              hipStream_t stream)
{
    const float* x      = (const float*)d_in[0];
    const float* W_in   = (const float*)d_in[1];
    const float* conv_w = (const float*)d_in[2];
    const float* conv_b = (const float*)d_in[3];
    const float* W_x    = (const float*)d_in[4];
    const float* W_dt   = (const float*)d_in[5];
    const float* b_dt   = (const float*)d_in[6];
    const float* A_log  = (const float*)d_in[7];
    const float* Dp     = (const float*)d_in[8];
    const float* W_out1 = (const float*)d_in[9];
    const float* W_out2 = (const float*)d_in[10];
    float* out = (float*)d_out;
    float* ws  = (float*)d_ws;

    // fp32 region (~170 MB)
    float* xz    = ws;                    // 16777216
    float* u     = xz    + 16777216;      //  8388608
    float* xdblp = u     + 8388608;       //   524288 (B*L x 128 padded)
    float* dtb   = xdblp + 524288;        //  8388608 (delta)
    float* ysc   = dtb   + 8388608;       //  8388608
    float* Aneg  = ysc   + 8388608;       //    32768
    float* S     = Aneg  + 32768;         //     4096
    // bf16 tail (50.3 MB)
    __bf16* ycat16 = (__bf16*)(S + 4096);          // 16777216 el
    __bf16* h16    = ycat16 + 16777216;            //  8388608 el
    // overlays (regions dead at time of use)
    __bf16* W_in16  = (__bf16*)u;                  // before conv writes u
    __bf16* xb16    = W_in16 + 4194304;
    __bf16* Wout116 = (__bf16*)dtb;                // after scan reads dtb
    __bf16* Wout216 = Wout116 + 8388608;
    // u_t (bf16 [B*L][D_INNER], 16.8MB) + scan summaries (12MB) inside ycat16 (33.5MB)
    __bf16* ut16  = ycat16;                        // 8388608 el
    float* chA    = (float*)(ut16 + 8388608);      // 1048576
    float* chS    = chA + 1048576;                 // 1048576
    float* sinitb = chS + 1048576;                 // 1048576
    // Wx bf16 padded [128][2048] inside h16 region (dead until out1 GEMM)
    __bf16* Wx16p = h16;                           // 262144 el

    hipMemsetAsync(S, 0, 4096 * sizeof(float), stream);
    aneg_k<<<128, 256, 0, stream>>>(A_log, Aneg);

    // bf16 conversions for input GEMM
    cvt_bf16_k<<<2048, 256, 0, stream>>>(W_in, W_in16, 524288);
    cvt_bf16_k<<<2048, 256, 0, stream>>>(x, xb16, 524288);
    // W_x -> bf16 (96 rows), zero-pad rows 96..127
    cvt_bf16_k<<<96, 256, 0, stream>>>(W_x, Wx16p, 24576);
    hipMemsetAsync(Wx16p + 96 * D_INNER, 0, 32 * D_INNER * sizeof(__bf16), stream);

    // xz[b,e,l] = sum_d W_in[e,d] * x[b,l,d]   (M=4096, N=2048, K=1024)
    gemm_bf16_k<0, 0><<<dim3(16, 32, BATCH), 256, 0, stream>>>(
        W_in16, xb16, xz, D_MODEL, D_MODEL, D_MODEL, SEQLEN,
        (long long)SEQLEN * D_MODEL, (long long)4096 * SEQLEN);

    conv_silu_k<<<dim3(SEQLEN / 32, D_INNER / 32, BATCH), dim3(32, 8), 0, stream>>>(
        xz, conv_w, conv_b, u, ut16);

    // x_dbl[b,l,e] = sum_d u_t[b,l,d] * Wx[e,d]  (MFMA: M=4096, N=128, K=2048)
    gemm_bf16_k<0, 0><<<dim3(1, 32, 1), 256, 0, stream>>>(
        ut16, Wx16p, xdblp, D_INNER, D_INNER, D_INNER, XSTR, 0LL, 0LL);

    // dt[b,d,l] = sum_r W_dt[d,r] * x_dbl[b,l,r]   (small K=64, fp32)
    gemm_nt_k<0><<<dim3(SEQLEN / 64, D_INNER / 64, BATCH), 256, 0, stream>>>(
        W_dt, xdblp, dtb, D_INNER, SEQLEN, DT_RANK, DT_RANK, XSTR, SEQLEN,
        0LL, (long long)SEQLEN * XSTR, (long long)D_INNER * SEQLEN);

    softplus_k<<<(BATCH * D_INNER * SEQLEN) / 256, 256, 0, stream>>>(dtb, b_dt);

    // chunked scan: 16x time-parallel
    scan_p1_k<<<(BATCH * D_INNER * NCHUNK) / 4, 64, 0, stream>>>(dtb, u, xdblp, Aneg, chA, chS);
    scan_comb_k<<<256, 256, 0, stream>>>(chA, chS, sinitb);
    scan_p3_k<<<(BATCH * D_INNER * NCHUNK) / 4, 64, 0, stream>>>(dtb, u, xdblp, Aneg, sinitb, ysc);

    // weight conversions for output GEMMs (dtb region dead now)
    cvt_bf16_k<<<4096, 256, 0, stream>>>(W_out1, Wout116, 1048576);
    cvt_bf16_k<<<1024, 256, 0, stream>>>(W_out2, Wout216, 262144);

    ssum_k<<<dim3((BATCH * SEQLEN) / 256, 8), 256, 0, stream>>>(u, Dp, S);

    ytrans_k<<<dim3(SEQLEN / 32, D_INNER / 32, BATCH), dim3(32, 8), 0, stream>>>(ysc, u, xz, Dp, ycat16);

    yt_k<<<dim3(SEQLEN / 32, D_INNER / 64, BATCH), 256, 0, stream>>>(xdblp, Aneg, S, ycat16);

    // h = relu(ycat @ W_out1^T) -> bf16   (M=4096, N=2048, K=4096)
    gemm_bf16_k<1, 1><<<dim3(16, 32, 1), 256, 0, stream>>>(
        ycat16, Wout116, h16, 2 * D_INNER, 2 * D_INNER, 2 * D_INNER, D_INNER, 0LL, 0LL);

    // out = h @ W_out2^T   (M=4096, N=1024, K=2048)
    gemm_bf16_k<0, 0><<<dim3(8, 32, 1), 256, 0, stream>>>(
        h16, Wout216, out, D_INNER, D_INNER, D_INNER, D_MODEL, 0LL, 0LL);
}

// Round 14
// 556.430 us; speedup vs baseline: 1.4834x; 1.0592x over previous
//
#include <hip/hip_runtime.h>
#include <hip/hip_bf16.h>
#include <math.h>

#define D_MODEL 1024
#define D_STATE 16
#define D_INNER 2048
#define DT_RANK 64
#define BATCH   2
#define SEQLEN  2048
#define NPROJ   96   // DT_RANK + 2*D_STATE (logical)
#define XSTR    128  // padded x_dbl row stride
#define NCHUNK  16
#define CHUNK   128  // SEQLEN / NCHUNK
#define XKS     8    // x_dbl GEMM K-split

typedef __attribute__((ext_vector_type(8))) __bf16 bf16x8;
typedef __attribute__((ext_vector_type(4))) float f32x4;

__device__ __forceinline__ float silu_f(float x) { return x / (1.f + __expf(-x)); }

__device__ __forceinline__ void gload_lds16(const void* g, void* l) {
    __builtin_amdgcn_global_load_lds((const __attribute__((address_space(1))) void*)g,
                                     (__attribute__((address_space(3))) void*)l, 16, 0, 0);
}

// ---------------- bf16 MFMA NT GEMM: C[m,n] = sum_k A[m,k]*B[n,k] -------------
// 128x128 tile, BK=32, 4 waves. Bijective XCD swizzle on (y,x) flat id.
// A/B/C all advance by blockIdx.z * {sA,sB,sC} (sA in elements along k).
template<int RELU, int OUT_BF16>
__global__ __launch_bounds__(256) void gemm_bf16_k(
    const __bf16* __restrict__ A, const __bf16* __restrict__ B, void* __restrict__ Cv,
    int K, int lda, int ldb, int ldc, long long sA, long long sB, long long sC)
{
    __shared__ alignas(16) __bf16 As[128 * 32];
    __shared__ alignas(16) __bf16 Bs[128 * 32];
    const int bz = blockIdx.z;
    A += (long long)bz * sA;
    B += (long long)bz * sB;
    // XCD-aware swizzle: consecutive swz ids land on the same XCD
    int nwg = gridDim.x * gridDim.y;
    int flat = blockIdx.y * gridDim.x + blockIdx.x;
    int swz = (nwg & 7) ? flat : ((flat & 7) * (nwg >> 3) + (flat >> 3));
    const int m0 = (swz / gridDim.x) * 128, n0 = (swz % gridDim.x) * 128;
    const int tid = threadIdx.x;
    const int lane = tid & 63;
    const int wv = tid >> 6;
    const int wr = wv >> 1, wc = wv & 1;

    f32x4 acc[4][4];
    #pragma unroll
    for (int i = 0; i < 4; ++i)
        #pragma unroll
        for (int j = 0; j < 4; ++j) acc[i][j] = (f32x4){0.f, 0.f, 0.f, 0.f};

    const int ko = (lane >> 4) * 8;
    const int fr = lane & 15;

    for (int k0 = 0; k0 < K; k0 += 32) {
        #pragma unroll
        for (int q = 0; q < 2; ++q) {
            int f = tid + q * 256;
            int row = f >> 2, c16 = f & 3;
            gload_lds16(A + (long long)(m0 + row) * lda + k0 + c16 * 8, As + f * 8);
            gload_lds16(B + (long long)(n0 + row) * ldb + k0 + c16 * 8, Bs + f * 8);
        }
        __syncthreads();
        bf16x8 a[4], b[4];
        #pragma unroll
        for (int i = 0; i < 4; ++i) {
            a[i] = *(const bf16x8*)(As + (wr * 64 + i * 16 + fr) * 32 + ko);
            b[i] = *(const bf16x8*)(Bs + (wc * 64 + i * 16 + fr) * 32 + ko);
        }
        #pragma unroll
        for (int i = 0; i < 4; ++i)
            #pragma unroll
            for (int j = 0; j < 4; ++j)
                acc[i][j] = __builtin_amdgcn_mfma_f32_16x16x32_bf16(a[i], b[j], acc[i][j], 0, 0, 0);
        __syncthreads();
    }

    #pragma unroll
    for (int i = 0; i < 4; ++i) {
        const int row = m0 + wr * 64 + i * 16 + (lane >> 4) * 4;
        #pragma unroll
        for (int j = 0; j < 4; ++j) {
            const int col = n0 + wc * 64 + j * 16 + fr;
            #pragma unroll
            for (int r = 0; r < 4; ++r) {
                float v = acc[i][j][r];
                if (RELU) v = fmaxf(v, 0.f);
                if (OUT_BF16)
                    ((__bf16*)Cv)[(long long)bz * sC + (long long)(row + r) * ldc + col] = (__bf16)v;
                else
                    ((float*)Cv)[(long long)bz * sC + (long long)(row + r) * ldc + col] = v;
            }
        }
    }
}

// ---------------- f32 -> bf16 pack (8 per thread) ----------------
__global__ void cvt_bf16_k(const float* __restrict__ in, __bf16* __restrict__ out, int n8) {
    int i = blockIdx.x * 256 + threadIdx.x;
    if (i >= n8) return;
    const f32x4* p = (const f32x4*)in + (long long)i * 2;
    f32x4 v0 = p[0], v1 = p[1];
    bf16x8 o;
    o[0] = (__bf16)v0[0]; o[1] = (__bf16)v0[1]; o[2] = (__bf16)v0[2]; o[3] = (__bf16)v0[3];
    o[4] = (__bf16)v1[0]; o[5] = (__bf16)v1[1]; o[6] = (__bf16)v1[2]; o[7] = (__bf16)v1[3];
    ((bf16x8*)out)[i] = o;
}

// ---------------- generic fp32 NT GEMM (dt GEMM; optional fused softplus) -----
template<int SOFTPLUS>
__global__ __launch_bounds__(256) void gemm_nt_k(
    const float* __restrict__ A, const float* __restrict__ B, float* __restrict__ C,
    const float* __restrict__ bias,
    int M, int N, int K, int lda, int ldb, int ldc,
    long long sA, long long sB, long long sC)
{
    __shared__ float As[16][68];
    __shared__ float Bs[16][68];
    const int bz = blockIdx.z;
    A += (long long)bz * sA; B += (long long)bz * sB; C += (long long)bz * sC;
    const int m0 = blockIdx.y * 64, n0 = blockIdx.x * 64;
    const int tid = threadIdx.x;
    const int lk = tid & 15, lr = tid >> 4;
    const int tx = tid & 15, ty = tid >> 4;
    float acc[4][4] = {};
    for (int k0 = 0; k0 < K; k0 += 16) {
        #pragma unroll
        for (int q = 0; q < 4; ++q) {
            int i = lr + q * 16;
            As[lk][i] = A[(long long)(m0 + i) * lda + k0 + lk];
            Bs[lk][i] = B[(long long)(n0 + i) * ldb + k0 + lk];
        }
        __syncthreads();
        #pragma unroll
        for (int k = 0; k < 16; ++k) {
            float a[4], b[4];
            #pragma unroll
            for (int j = 0; j < 4; ++j) { a[j] = As[k][ty*4+j]; b[j] = Bs[k][tx*4+j]; }
            #pragma unroll
            for (int i = 0; i < 4; ++i)
                #pragma unroll
                for (int j = 0; j < 4; ++j) acc[i][j] += a[i] * b[j];
        }
        __syncthreads();
    }
    #pragma unroll
    for (int i = 0; i < 4; ++i) {
        const int m = m0 + ty * 4 + i;
        float bi = SOFTPLUS ? bias[m] : 0.f;
        #pragma unroll
        for (int j = 0; j < 4; ++j) {
            float v = acc[i][j];
            if (SOFTPLUS) {
                v += bi;
                v = fmaxf(v, 0.f) + log1pf(expf(-fabsf(v)));
            }
            C[(long long)m * ldc + n0 + tx*4 + j] = v;
        }
    }
}

// ---------------- Aneg = -exp(A_log) ----------------
__global__ void aneg_k(const float* __restrict__ A_log, float* __restrict__ Aneg) {
    int i = blockIdx.x * 256 + threadIdx.x;
    if (i < D_INNER * D_STATE) Aneg[i] = -expf(A_log[i]);
}

// ---------------- depthwise causal conv(4) + bias + SiLU, dual-layout out -----
__global__ __launch_bounds__(256) void conv_silu_k(const float* __restrict__ xz,
    const float* __restrict__ cw, const float* __restrict__ cb,
    float* __restrict__ u, __bf16* __restrict__ ut)
{
    __shared__ float tile[32][33];
    const int b = blockIdx.z;
    const int d0 = blockIdx.y * 32, l0 = blockIdx.x * 32;
    const int lx = threadIdx.x, dy = threadIdx.y;   // (32,8)
    #pragma unroll
    for (int j = 0; j < 4; ++j) {
        int d = d0 + dy + j * 8;
        const float* xi = xz + ((long long)b * 2 * D_INNER + d) * SEQLEN;
        int l = l0 + lx;
        float acc = cb[d];
        #pragma unroll
        for (int k = 0; k < 4; ++k) {
            int t = l + k - 3;
            if (t >= 0) acc += xi[t] * cw[d * 4 + k];
        }
        float v = silu_f(acc);
        u[((long long)b * D_INNER + d) * SEQLEN + l] = v;
        tile[dy + j * 8][lx] = v;
    }
    __syncthreads();
    #pragma unroll
    for (int j = 0; j < 4; ++j) {
        int l = l0 + dy + j * 8;
        ut[((long long)b * SEQLEN + l) * D_INNER + d0 + lx] = (__bf16)tile[lx][dy + j * 8];
    }
}

// ---------------- reduce XKS x_dbl partials -> xdblp ----------------
__global__ void xdbl_red_k(const float* __restrict__ xpart, float* __restrict__ xdbl) {
    int i = blockIdx.x * 256 + threadIdx.x;    // over 131072 float4s
    const f32x4* p = (const f32x4*)xpart;
    f32x4 s = p[i];
    #pragma unroll
    for (int ks = 1; ks < XKS; ++ks) {
        f32x4 v = p[(long long)ks * (BATCH * SEQLEN * XSTR / 4) + i];
        s.x += v.x; s.y += v.y; s.z += v.z; s.w += v.w;
    }
    ((f32x4*)xdbl)[i] = s;
}

// ======== chunked selective scan: time-parallel via associative combine =======
__global__ __launch_bounds__(64, 1) void scan_p1_k(const float* __restrict__ delta,
    const float* __restrict__ u, const float* __restrict__ xdbl,
    const float* __restrict__ Aneg, float* __restrict__ chA, float* __restrict__ chS)
{
    const int q = threadIdx.x >> 4;
    const int n = threadIdx.x & 15;
    const int gg = blockIdx.x * 4 + q;
    const int g = gg >> 4, c = gg & (NCHUNK - 1);
    const int b = g >> 11, d = g & (D_INNER - 1);
    const float a = Aneg[d * D_STATE + n];
    const long long base = (long long)g * SEQLEN + c * CHUNK;
    const float4* dv = (const float4*)(delta + base);
    const float4* uv = (const float4*)(u + base);
    const float* xb = xdbl + ((long long)b * SEQLEN + c * CHUNK) * XSTR + DT_RANK + n;

    float4 pd[4], pu[4];
    float pB[16];
    #pragma unroll
    for (int i = 0; i < 4; ++i) { pd[i] = dv[i]; pu[i] = uv[i]; }
    #pragma unroll
    for (int i = 0; i < 16; ++i) pB[i] = xb[i * XSTR];

    float s = 0.f, ap = 1.f;
    for (int t0 = 0; t0 < CHUNK; t0 += 16) {
        float cd[16], cu[16], cB[16];
        #pragma unroll
        for (int i = 0; i < 4; ++i) {
            cd[4*i] = pd[i].x; cd[4*i+1] = pd[i].y; cd[4*i+2] = pd[i].z; cd[4*i+3] = pd[i].w;
            cu[4*i] = pu[i].x; cu[4*i+1] = pu[i].y; cu[4*i+2] = pu[i].z; cu[4*i+3] = pu[i].w;
        }
        #pragma unroll
        for (int i = 0; i < 16; ++i) cB[i] = pB[i];
        if (t0 + 16 < CHUNK) {
            const int nb = (t0 >> 2) + 4;
            #pragma unroll
            for (int i = 0; i < 4; ++i) { pd[i] = dv[nb + i]; pu[i] = uv[nb + i]; }
            const float* xn = xb + (t0 + 16) * XSTR;
            #pragma unroll
            for (int i = 0; i < 16; ++i) pB[i] = xn[i * XSTR];
        }
        float dA[16], wB[16];
        #pragma unroll
        for (int i = 0; i < 16; ++i) {
            dA[i] = __expf(cd[i] * a);
            wB[i] = cd[i] * cu[i] * cB[i];
        }
        #pragma unroll
        for (int i = 0; i < 16; ++i) {
            s = dA[i] * s + wB[i];
            ap *= dA[i];
        }
    }
    chA[(long long)gg * 16 + n] = ap;
    chS[(long long)gg * 16 + n] = s;
}

__global__ void scan_comb_k(const float* __restrict__ chA, const float* __restrict__ chS,
                            float* __restrict__ sinit)
{
    int idx = blockIdx.x * 256 + threadIdx.x;      // (g, n), 65536 total
    int g = idx >> 4, n = idx & 15;
    const float* A = chA + (long long)g * (NCHUNK * 16) + n;
    const float* S = chS + (long long)g * (NCHUNK * 16) + n;
    float av[NCHUNK], sv[NCHUNK];
    #pragma unroll
    for (int c = 0; c < NCHUNK; ++c) { av[c] = A[c * 16]; sv[c] = S[c * 16]; }
    float* si = sinit + (long long)g * (NCHUNK * 16) + n;
    float carry = 0.f;
    #pragma unroll
    for (int c = 0; c < NCHUNK; ++c) {
        si[c * 16] = carry;
        carry = sv[c] + av[c] * carry;
    }
}

__global__ __launch_bounds__(64, 1) void scan_p3_k(const float* __restrict__ delta,
    const float* __restrict__ u, const float* __restrict__ xdbl,
    const float* __restrict__ Aneg, const float* __restrict__ sinit, float* __restrict__ y)
{
    __shared__ float lp[4][16][17];
    const int q = threadIdx.x >> 4;
    const int n = threadIdx.x & 15;
    const int gg = blockIdx.x * 4 + q;
    const int g = gg >> 4, c = gg & (NCHUNK - 1);
    const int b = g >> 11, d = g & (D_INNER - 1);
    const float a = Aneg[d * D_STATE + n];
    const long long base = (long long)g * SEQLEN + c * CHUNK;
    const float4* dv = (const float4*)(delta + base);
    const float4* uv = (const float4*)(u + base);
    const float* xb = xdbl + ((long long)b * SEQLEN + c * CHUNK) * XSTR + DT_RANK + n;
    float* yl = y + base;

    float4 pd[4], pu[4];
    float pB[16], pC[16];
    #pragma unroll
    for (int i = 0; i < 4; ++i) { pd[i] = dv[i]; pu[i] = uv[i]; }
    #pragma unroll
    for (int i = 0; i < 16; ++i) { pB[i] = xb[i * XSTR]; pC[i] = xb[i * XSTR + D_STATE]; }

    float s = sinit[(long long)gg * 16 + n];
    for (int t0 = 0; t0 < CHUNK; t0 += 16) {
        float cd[16], cu[16], cB[16], cC[16];
        #pragma unroll
        for (int i = 0; i < 4; ++i) {
            cd[4*i] = pd[i].x; cd[4*i+1] = pd[i].y; cd[4*i+2] = pd[i].z; cd[4*i+3] = pd[i].w;
            cu[4*i] = pu[i].x; cu[4*i+1] = pu[i].y; cu[4*i+2] = pu[i].z; cu[4*i+3] = pu[i].w;
        }
        #pragma unroll
        for (int i = 0; i < 16; ++i) { cB[i] = pB[i]; cC[i] = pC[i]; }
        if (t0 + 16 < CHUNK) {
            const int nb = (t0 >> 2) + 4;
            #pragma unroll
            for (int i = 0; i < 4; ++i) { pd[i] = dv[nb + i]; pu[i] = uv[nb + i]; }
            const float* xn = xb + (t0 + 16) * XSTR;
            #pragma unroll
            for (int i = 0; i < 16; ++i) { pB[i] = xn[i * XSTR]; pC[i] = xn[i * XSTR + D_STATE]; }
        }
        float dA[16], wB[16];
        #pragma unroll
        for (int i = 0; i < 16; ++i) {
            dA[i] = __expf(cd[i] * a);
            wB[i] = cd[i] * cu[i] * cB[i];
        }
        #pragma unroll
        for (int i = 0; i < 16; ++i) {
            s = dA[i] * s + wB[i];
            lp[q][n][i] = s * cC[i];
        }
        __syncthreads();
        float v[16];
        #pragma unroll
        for (int j = 0; j < 16; ++j) v[j] = lp[q][j][n];
        float acc = 0.f;
        #pragma unroll
        for (int j = 0; j < 16; ++j) acc += v[j];
        yl[t0 + n] = acc;
        __syncthreads();
    }
}

// ---------------- S[b,l] = sum_d Dp[d]*u[b,d,l] ----------------
__global__ void ssum_k(const float* __restrict__ u, const float* __restrict__ Dp,
                       float* __restrict__ S)
{
    int li = blockIdx.x * 256 + threadIdx.x;
    int c = blockIdx.y;
    int b = li >> 11, l = li & (SEQLEN - 1);
    const float* up = u + (long long)b * D_INNER * SEQLEN + l;
    float acc = 0.f;
    for (int d = c * 256; d < c * 256 + 256; ++d)
        acc += Dp[d] * up[(long long)d * SEQLEN];
    atomicAdd(&S[li], acc);
}

// ---------------- y=(y+Dp*u)*silu(z), transposed into ycat16[...,:2048] -------
__global__ __launch_bounds__(256) void ytrans_k(const float* __restrict__ ysc,
    const float* __restrict__ u, const float* __restrict__ xz,
    const float* __restrict__ Dp, __bf16* __restrict__ ycat)
{
    __shared__ float tile[32][33];
    const int b = blockIdx.z;
    const int d0 = blockIdx.y * 32, l0 = blockIdx.x * 32;
    const int lx = threadIdx.x, dy = threadIdx.y;
    #pragma unroll
    for (int j = 0; j < 4; ++j) {
        int d = d0 + dy + j * 8;
        long long i  = ((long long)b * D_INNER + d) * SEQLEN + l0 + lx;
        long long iz = ((long long)b * 2 * D_INNER + D_INNER + d) * SEQLEN + l0 + lx;
        tile[dy + j * 8][lx] = (ysc[i] + Dp[d] * u[i]) * silu_f(xz[iz]);
    }
    __syncthreads();
    #pragma unroll
    for (int j = 0; j < 4; ++j) {
        int l = l0 + dy + j * 8;
        ycat[((long long)b * SEQLEN + l) * (2 * D_INNER) + d0 + lx] = (__bf16)tile[lx][dy + j * 8];
    }
}

// ---------------- y_t -> ycat16[...,2048:] ----------------
__global__ __launch_bounds__(256) void yt_k(const float* __restrict__ xdbl,
    const float* __restrict__ Aneg, const float* __restrict__ S, __bf16* __restrict__ ycat)
{
    __shared__ float Cs[16][33];
    __shared__ float An[16][64];
    __shared__ float Sv[32];
    const int b = blockIdx.z;
    const int d0 = blockIdx.y * 64, l0 = blockIdx.x * 32;
    const int tid = threadIdx.x;
    for (int f = tid; f < 512; f += 256) {
        int n = f & 15, l = f >> 4;
        Cs[n][l] = xdbl[((long long)b * SEQLEN + l0 + l) * XSTR + DT_RANK + D_STATE + n];
    }
    for (int f = tid; f < 1024; f += 256) {
        int n = f & 15, d = f >> 4;
        An[n][d] = Aneg[(d0 + d) * D_STATE + n];
    }
    if (tid < 32) Sv[tid] = S[b * SEQLEN + l0 + tid];
    __syncthreads();
    const int dx = tid & 63, lg = tid >> 6;
    #pragma unroll
    for (int j = 0; j < 8; ++j) {
        int l = lg * 8 + j;
        float acc = Sv[l];
        #pragma unroll
        for (int n = 0; n < 16; ++n) acc += Cs[n][l] * An[n][dx];
        ycat[((long long)b * SEQLEN + l0 + l) * (2 * D_INNER) + D_INNER + d0 + dx] = (__bf16)acc;
    }
}

extern "C" void kernel_launch(void* const* d_in, const int* in_sizes, int n_in,
                              void* d_out, int out_size, void* d_ws, size_t ws_size,
                              hipStream_t stream)
{
    const float* x      = (const float*)d_in[0];
    const float* W_in   = (const float*)d_in[1];
    const float* conv_w = (const float*)d_in[2];
    const float* conv_b = (const float*)d_in[3];
    const float* W_x    = (const float*)d_in[4];
    const float* W_dt   = (const float*)d_in[5];
    const float* b_dt   = (const float*)d_in[6];
    const float* A_log  = (const float*)d_in[7];
    const float* Dp     = (const float*)d_in[8];
    const float* W_out1 = (const float*)d_in[9];
    const float* W_out2 = (const float*)d_in[10];
    float* out = (float*)d_out;
    float* ws  = (float*)d_ws;

    // fp32 region (~170 MB)
    float* xz    = ws;                    // 16777216
    float* u     = xz    + 16777216;      //  8388608
    float* xdblp = u     + 8388608;       //   524288 (B*L x 128 padded)
    float* dtb   = xdblp + 524288;        //  8388608 (delta)
    float* ysc   = dtb   + 8388608;       //  8388608
    float* Aneg  = ysc   + 8388608;       //    32768
    float* S     = Aneg  + 32768;         //     4096
    // bf16 tail (50.3 MB)
    __bf16* ycat16 = (__bf16*)(S + 4096);          // 16777216 el
    __bf16* h16    = ycat16 + 16777216;            //  8388608 el
    // overlays (regions dead at time of use)
    __bf16* W_in16  = (__bf16*)u;                  // before conv writes u
    __bf16* xb16    = W_in16 + 4194304;
    __bf16* Wout116 = (__bf16*)dtb;                // after scan reads dtb
    __bf16* Wout216 = Wout116 + 8388608;
    // u_t (bf16 [B*L][D_INNER], 16.8MB) + scan summaries (12MB) inside ycat16 (33.5MB)
    __bf16* ut16  = ycat16;                        // 8388608 el
    float* chA    = (float*)(ut16 + 8388608);      // 1048576
    float* chS    = chA + 1048576;                 // 1048576
    float* sinitb = chS + 1048576;                 // 1048576
    // Wx bf16 padded [128][2048] inside h16 region (dead until out1 GEMM)
    __bf16* Wx16p = h16;                           // 262144 el
    // x_dbl K-split partials overlay dtb (dead until dt GEMM): 8*524288 floats
    float* xpart  = dtb;

    hipMemsetAsync(S, 0, 4096 * sizeof(float), stream);
    aneg_k<<<128, 256, 0, stream>>>(A_log, Aneg);

    // bf16 conversions for input GEMM
    cvt_bf16_k<<<2048, 256, 0, stream>>>(W_in, W_in16, 524288);
    cvt_bf16_k<<<2048, 256, 0, stream>>>(x, xb16, 524288);
    // W_x -> bf16 (96 rows), zero-pad rows 96..127
    cvt_bf16_k<<<96, 256, 0, stream>>>(W_x, Wx16p, 24576);
    hipMemsetAsync(Wx16p + 96 * D_INNER, 0, 32 * D_INNER * sizeof(__bf16), stream);

    // xz[b,e,l] = sum_d W_in[e,d] * x[b,l,d]   (M=4096, N=2048, K=1024)
    gemm_bf16_k<0, 0><<<dim3(16, 32, BATCH), 256, 0, stream>>>(
        W_in16, xb16, xz, D_MODEL, D_MODEL, D_MODEL, SEQLEN,
        0LL, (long long)SEQLEN * D_MODEL, (long long)4096 * SEQLEN);

    conv_silu_k<<<dim3(SEQLEN / 32, D_INNER / 32, BATCH), dim3(32, 8), 0, stream>>>(
        xz, conv_w, conv_b, u, ut16);

    // x_dbl partials: K-split=8 (z selects k-range via sA/sB), 256 blocks
    gemm_bf16_k<0, 0><<<dim3(1, 32, XKS), 256, 0, stream>>>(
        ut16, Wx16p, xpart, D_INNER / XKS, D_INNER, D_INNER, XSTR,
        (long long)(D_INNER / XKS), (long long)(D_INNER / XKS),
        (long long)BATCH * SEQLEN * XSTR);
    xdbl_red_k<<<(BATCH * SEQLEN * XSTR / 4) / 256, 256, 0, stream>>>(xpart, xdblp);

    // dt[b,d,l] = softplus(sum_r W_dt[d,r] * x_dbl[b,l,r] + b_dt[d])  (fused)
    gemm_nt_k<1><<<dim3(SEQLEN / 64, D_INNER / 64, BATCH), 256, 0, stream>>>(
        W_dt, xdblp, dtb, b_dt, D_INNER, SEQLEN, DT_RANK, DT_RANK, XSTR, SEQLEN,
        0LL, (long long)SEQLEN * XSTR, (long long)D_INNER * SEQLEN);

    // chunked scan: 16x time-parallel
    scan_p1_k<<<(BATCH * D_INNER * NCHUNK) / 4, 64, 0, stream>>>(dtb, u, xdblp, Aneg, chA, chS);
    scan_comb_k<<<256, 256, 0, stream>>>(chA, chS, sinitb);
    scan_p3_k<<<(BATCH * D_INNER * NCHUNK) / 4, 64, 0, stream>>>(dtb, u, xdblp, Aneg, sinitb, ysc);

    // weight conversions for output GEMMs (dtb region dead now)
    cvt_bf16_k<<<4096, 256, 0, stream>>>(W_out1, Wout116, 1048576);
    cvt_bf16_k<<<1024, 256, 0, stream>>>(W_out2, Wout216, 262144);

    ssum_k<<<dim3((BATCH * SEQLEN) / 256, 8), 256, 0, stream>>>(u, Dp, S);

    ytrans_k<<<dim3(SEQLEN / 32, D_INNER / 32, BATCH), dim3(32, 8), 0, stream>>>(ysc, u, xz, Dp, ycat16);

    yt_k<<<dim3(SEQLEN / 32, D_INNER / 64, BATCH), 256, 0, stream>>>(xdblp, Aneg, S, ycat16);

    // h = relu(ycat @ W_out1^T) -> bf16   (M=4096, N=2048, K=4096)
    gemm_bf16_k<1, 1><<<dim3(16, 32, 1), 256, 0, stream>>>(
        ycat16, Wout116, h16, 2 * D_INNER, 2 * D_INNER, 2 * D_INNER, D_INNER,
        0LL, 0LL, 0LL);

    // out = h @ W_out2^T   (M=4096, N=1024, K=2048)
    gemm_bf16_k<0, 0><<<dim3(8, 32, 1), 256, 0, stream>>>(
        h16, Wout216, out, D_INNER, D_INNER, D_INNER, D_MODEL,
        0LL, 0LL, 0LL);
}

// Round 15
// 544.446 us; speedup vs baseline: 1.5160x; 1.0220x over previous
//
#include <hip/hip_runtime.h>
#include <hip/hip_bf16.h>
#include <math.h>

#define D_MODEL 1024
#define D_STATE 16
#define D_INNER 2048
#define DT_RANK 64
#define BATCH   2
#define SEQLEN  2048
#define NPROJ   96   // DT_RANK + 2*D_STATE (logical)
#define XSTR    128  // padded x_dbl row stride
#define NCHUNK  16
#define CHUNK   128  // SEQLEN / NCHUNK
#define XKS     8    // x_dbl GEMM K-split

typedef __attribute__((ext_vector_type(8))) __bf16 bf16x8;
typedef __attribute__((ext_vector_type(4))) float f32x4;

__device__ __forceinline__ float silu_f(float x) { return x / (1.f + __expf(-x)); }

__device__ __forceinline__ void gload_lds16(const void* g, void* l) {
    __builtin_amdgcn_global_load_lds((const __attribute__((address_space(1))) void*)g,
                                     (__attribute__((address_space(3))) void*)l, 16, 0, 0);
}

// ---------------- bf16 MFMA NT GEMM: C[m,n] = sum_k A[m,k]*B[n,k] -------------
// 128x128 tile, BK=32, 4 waves. Bijective XCD swizzle on (y,x) flat id.
template<int RELU, int OUT_BF16>
__global__ __launch_bounds__(256) void gemm_bf16_k(
    const __bf16* __restrict__ A, const __bf16* __restrict__ B, void* __restrict__ Cv,
    int K, int lda, int ldb, int ldc, long long sA, long long sB, long long sC)
{
    __shared__ alignas(16) __bf16 As[128 * 32];
    __shared__ alignas(16) __bf16 Bs[128 * 32];
    const int bz = blockIdx.z;
    A += (long long)bz * sA;
    B += (long long)bz * sB;
    int nwg = gridDim.x * gridDim.y;
    int flat = blockIdx.y * gridDim.x + blockIdx.x;
    int swz = (nwg & 7) ? flat : ((flat & 7) * (nwg >> 3) + (flat >> 3));
    const int m0 = (swz / gridDim.x) * 128, n0 = (swz % gridDim.x) * 128;
    const int tid = threadIdx.x;
    const int lane = tid & 63;
    const int wv = tid >> 6;
    const int wr = wv >> 1, wc = wv & 1;

    f32x4 acc[4][4];
    #pragma unroll
    for (int i = 0; i < 4; ++i)
        #pragma unroll
        for (int j = 0; j < 4; ++j) acc[i][j] = (f32x4){0.f, 0.f, 0.f, 0.f};

    const int ko = (lane >> 4) * 8;
    const int fr = lane & 15;

    for (int k0 = 0; k0 < K; k0 += 32) {
        #pragma unroll
        for (int q = 0; q < 2; ++q) {
            int f = tid + q * 256;
            int row = f >> 2, c16 = f & 3;
            gload_lds16(A + (long long)(m0 + row) * lda + k0 + c16 * 8, As + f * 8);
            gload_lds16(B + (long long)(n0 + row) * ldb + k0 + c16 * 8, Bs + f * 8);
        }
        __syncthreads();
        bf16x8 a[4], b[4];
        #pragma unroll
        for (int i = 0; i < 4; ++i) {
            a[i] = *(const bf16x8*)(As + (wr * 64 + i * 16 + fr) * 32 + ko);
            b[i] = *(const bf16x8*)(Bs + (wc * 64 + i * 16 + fr) * 32 + ko);
        }
        #pragma unroll
        for (int i = 0; i < 4; ++i)
            #pragma unroll
            for (int j = 0; j < 4; ++j)
                acc[i][j] = __builtin_amdgcn_mfma_f32_16x16x32_bf16(a[i], b[j], acc[i][j], 0, 0, 0);
        __syncthreads();
    }

    #pragma unroll
    for (int i = 0; i < 4; ++i) {
        const int row = m0 + wr * 64 + i * 16 + (lane >> 4) * 4;
        #pragma unroll
        for (int j = 0; j < 4; ++j) {
            const int col = n0 + wc * 64 + j * 16 + fr;
            #pragma unroll
            for (int r = 0; r < 4; ++r) {
                float v = acc[i][j][r];
                if (RELU) v = fmaxf(v, 0.f);
                if (OUT_BF16)
                    ((__bf16*)Cv)[(long long)bz * sC + (long long)(row + r) * ldc + col] = (__bf16)v;
                else
                    ((float*)Cv)[(long long)bz * sC + (long long)(row + r) * ldc + col] = v;
            }
        }
    }
}

// ---------------- f32 -> bf16 pack (8 per thread) ----------------
__global__ void cvt_bf16_k(const float* __restrict__ in, __bf16* __restrict__ out, int n8) {
    int i = blockIdx.x * 256 + threadIdx.x;
    if (i >= n8) return;
    const f32x4* p = (const f32x4*)in + (long long)i * 2;
    f32x4 v0 = p[0], v1 = p[1];
    bf16x8 o;
    o[0] = (__bf16)v0[0]; o[1] = (__bf16)v0[1]; o[2] = (__bf16)v0[2]; o[3] = (__bf16)v0[3];
    o[4] = (__bf16)v1[0]; o[5] = (__bf16)v1[1]; o[6] = (__bf16)v1[2]; o[7] = (__bf16)v1[3];
    ((bf16x8*)out)[i] = o;
}

// ---------------- generic fp32 NT GEMM (dt GEMM; fused softplus) --------------
template<int SOFTPLUS>
__global__ __launch_bounds__(256) void gemm_nt_k(
    const float* __restrict__ A, const float* __restrict__ B, float* __restrict__ C,
    const float* __restrict__ bias,
    int M, int N, int K, int lda, int ldb, int ldc,
    long long sA, long long sB, long long sC)
{
    __shared__ float As[16][68];
    __shared__ float Bs[16][68];
    const int bz = blockIdx.z;
    A += (long long)bz * sA; B += (long long)bz * sB; C += (long long)bz * sC;
    const int m0 = blockIdx.y * 64, n0 = blockIdx.x * 64;
    const int tid = threadIdx.x;
    const int lk = tid & 15, lr = tid >> 4;
    const int tx = tid & 15, ty = tid >> 4;
    float acc[4][4] = {};
    for (int k0 = 0; k0 < K; k0 += 16) {
        #pragma unroll
        for (int q = 0; q < 4; ++q) {
            int i = lr + q * 16;
            As[lk][i] = A[(long long)(m0 + i) * lda + k0 + lk];
            Bs[lk][i] = B[(long long)(n0 + i) * ldb + k0 + lk];
        }
        __syncthreads();
        #pragma unroll
        for (int k = 0; k < 16; ++k) {
            float a[4], b[4];
            #pragma unroll
            for (int j = 0; j < 4; ++j) { a[j] = As[k][ty*4+j]; b[j] = Bs[k][tx*4+j]; }
            #pragma unroll
            for (int i = 0; i < 4; ++i)
                #pragma unroll
                for (int j = 0; j < 4; ++j) acc[i][j] += a[i] * b[j];
        }
        __syncthreads();
    }
    #pragma unroll
    for (int i = 0; i < 4; ++i) {
        const int m = m0 + ty * 4 + i;
        float bi = SOFTPLUS ? bias[m] : 0.f;
        #pragma unroll
        for (int j = 0; j < 4; ++j) {
            float v = acc[i][j];
            if (SOFTPLUS) {
                v += bi;
                v = fmaxf(v, 0.f) + log1pf(expf(-fabsf(v)));
            }
            C[(long long)m * ldc + n0 + tx*4 + j] = v;
        }
    }
}

// ---------------- Aneg = -exp(A_log) ----------------
__global__ void aneg_k(const float* __restrict__ A_log, float* __restrict__ Aneg) {
    int i = blockIdx.x * 256 + threadIdx.x;
    if (i < D_INNER * D_STATE) Aneg[i] = -expf(A_log[i]);
}

// ---------------- depthwise causal conv(4) + bias + SiLU, dual-layout out -----
__global__ __launch_bounds__(256) void conv_silu_k(const float* __restrict__ xz,
    const float* __restrict__ cw, const float* __restrict__ cb,
    float* __restrict__ u, __bf16* __restrict__ ut)
{
    __shared__ float tile[32][33];
    const int b = blockIdx.z;
    const int d0 = blockIdx.y * 32, l0 = blockIdx.x * 32;
    const int lx = threadIdx.x, dy = threadIdx.y;   // (32,8)
    #pragma unroll
    for (int j = 0; j < 4; ++j) {
        int d = d0 + dy + j * 8;
        const float* xi = xz + ((long long)b * 2 * D_INNER + d) * SEQLEN;
        int l = l0 + lx;
        float acc = cb[d];
        #pragma unroll
        for (int k = 0; k < 4; ++k) {
            int t = l + k - 3;
            if (t >= 0) acc += xi[t] * cw[d * 4 + k];
        }
        float v = silu_f(acc);
        u[((long long)b * D_INNER + d) * SEQLEN + l] = v;
        tile[dy + j * 8][lx] = v;
    }
    __syncthreads();
    #pragma unroll
    for (int j = 0; j < 4; ++j) {
        int l = l0 + dy + j * 8;
        ut[((long long)b * SEQLEN + l) * D_INNER + d0 + lx] = (__bf16)tile[lx][dy + j * 8];
    }
}

// ---------------- reduce XKS x_dbl partials -> xdblp ----------------
__global__ void xdbl_red_k(const float* __restrict__ xpart, float* __restrict__ xdbl) {
    int i = blockIdx.x * 256 + threadIdx.x;
    const f32x4* p = (const f32x4*)xpart;
    f32x4 s = p[i];
    #pragma unroll
    for (int ks = 1; ks < XKS; ++ks) {
        f32x4 v = p[(long long)ks * (BATCH * SEQLEN * XSTR / 4) + i];
        s.x += v.x; s.y += v.y; s.z += v.z; s.w += v.w;
    }
    ((f32x4*)xdbl)[i] = s;
}

// ======== fused chunked selective scan: one block per chain ===================
// 256 threads: tid = c*16+n (c = chunk, n = state). Pass 1: per-chunk (A,S)
// summaries. LDS combine (16 serial steps). Pass 2: re-scan from sinit, emit y
// via padded-LDS transpose-reduce. Pass-2 re-reads are L1/L2-hot.
__global__ __launch_bounds__(256, 1) void scan_f_k(const float* __restrict__ delta,
    const float* __restrict__ u, const float* __restrict__ xdbl,
    const float* __restrict__ Aneg, float* __restrict__ y)
{
    __shared__ float combA[NCHUNK][16];
    __shared__ float combS[NCHUNK][16];
    __shared__ float sins[NCHUNK][16];
    __shared__ float lp[NCHUNK][16][17];
    const int tid = threadIdx.x;
    const int c = tid >> 4, n = tid & 15;
    const int g = blockIdx.x;              // chain id = b*D_INNER + d
    const int b = g >> 11, d = g & (D_INNER - 1);
    const float a = Aneg[d * D_STATE + n];
    const long long base = (long long)g * SEQLEN + c * CHUNK;
    const float4* dv = (const float4*)(delta + base);
    const float4* uv = (const float4*)(u + base);
    const float* xb = xdbl + ((long long)b * SEQLEN + c * CHUNK) * XSTR + DT_RANK + n;

    // ---- pass 1: chunk-local scan from 0, accumulate A = prod dA ----
    float4 pd[4], pu[4];
    float pB[16];
    #pragma unroll
    for (int i = 0; i < 4; ++i) { pd[i] = dv[i]; pu[i] = uv[i]; }
    #pragma unroll
    for (int i = 0; i < 16; ++i) pB[i] = xb[i * XSTR];

    float s = 0.f, ap = 1.f;
    for (int t0 = 0; t0 < CHUNK; t0 += 16) {
        float cd[16], cu[16], cB[16];
        #pragma unroll
        for (int i = 0; i < 4; ++i) {
            cd[4*i] = pd[i].x; cd[4*i+1] = pd[i].y; cd[4*i+2] = pd[i].z; cd[4*i+3] = pd[i].w;
            cu[4*i] = pu[i].x; cu[4*i+1] = pu[i].y; cu[4*i+2] = pu[i].z; cu[4*i+3] = pu[i].w;
        }
        #pragma unroll
        for (int i = 0; i < 16; ++i) cB[i] = pB[i];
        if (t0 + 16 < CHUNK) {
            const int nb = (t0 >> 2) + 4;
            #pragma unroll
            for (int i = 0; i < 4; ++i) { pd[i] = dv[nb + i]; pu[i] = uv[nb + i]; }
            const float* xn = xb + (t0 + 16) * XSTR;
            #pragma unroll
            for (int i = 0; i < 16; ++i) pB[i] = xn[i * XSTR];
        }
        float dA[16], wB[16];
        #pragma unroll
        for (int i = 0; i < 16; ++i) {
            dA[i] = __expf(cd[i] * a);
            wB[i] = cd[i] * cu[i] * cB[i];
        }
        #pragma unroll
        for (int i = 0; i < 16; ++i) {
            s = dA[i] * s + wB[i];
            ap *= dA[i];
        }
    }
    combA[c][n] = ap;
    combS[c][n] = s;
    __syncthreads();

    // ---- combine: 16 threads (c==0) do the serial 16-chunk prefix ----
    if (c == 0) {
        float av[NCHUNK], sv[NCHUNK];
        #pragma unroll
        for (int cc = 0; cc < NCHUNK; ++cc) { av[cc] = combA[cc][n]; sv[cc] = combS[cc][n]; }
        float carry = 0.f;
        #pragma unroll
        for (int cc = 0; cc < NCHUNK; ++cc) {
            sins[cc][n] = carry;
            carry = sv[cc] + av[cc] * carry;
        }
    }
    __syncthreads();

    // ---- pass 2: re-scan from sinit, emit y ----
    float* yl = y + base;
    float pC[16];
    #pragma unroll
    for (int i = 0; i < 4; ++i) { pd[i] = dv[i]; pu[i] = uv[i]; }
    #pragma unroll
    for (int i = 0; i < 16; ++i) { pB[i] = xb[i * XSTR]; pC[i] = xb[i * XSTR + D_STATE]; }

    s = sins[c][n];
    for (int t0 = 0; t0 < CHUNK; t0 += 16) {
        float cd[16], cu[16], cB[16], cC[16];
        #pragma unroll
        for (int i = 0; i < 4; ++i) {
            cd[4*i] = pd[i].x; cd[4*i+1] = pd[i].y; cd[4*i+2] = pd[i].z; cd[4*i+3] = pd[i].w;
            cu[4*i] = pu[i].x; cu[4*i+1] = pu[i].y; cu[4*i+2] = pu[i].z; cu[4*i+3] = pu[i].w;
        }
        #pragma unroll
        for (int i = 0; i < 16; ++i) { cB[i] = pB[i]; cC[i] = pC[i]; }
        if (t0 + 16 < CHUNK) {
            const int nb = (t0 >> 2) + 4;
            #pragma unroll
            for (int i = 0; i < 4; ++i) { pd[i] = dv[nb + i]; pu[i] = uv[nb + i]; }
            const float* xn = xb + (t0 + 16) * XSTR;
            #pragma unroll
            for (int i = 0; i < 16; ++i) { pB[i] = xn[i * XSTR]; pC[i] = xn[i * XSTR + D_STATE]; }
        }
        float dA[16], wB[16];
        #pragma unroll
        for (int i = 0; i < 16; ++i) {
            dA[i] = __expf(cd[i] * a);
            wB[i] = cd[i] * cu[i] * cB[i];
        }
        #pragma unroll
        for (int i = 0; i < 16; ++i) {
            s = dA[i] * s + wB[i];
            lp[c][n][i] = s * cC[i];
        }
        __syncthreads();
        float v[16];
        #pragma unroll
        for (int j = 0; j < 16; ++j) v[j] = lp[c][j][n];
        float acc = 0.f;
        #pragma unroll
        for (int j = 0; j < 16; ++j) acc += v[j];
        yl[t0 + n] = acc;
        __syncthreads();
    }
}

// ---------------- S[b,l] = sum_d Dp[d]*u[b,d,l] ----------------
__global__ void ssum_k(const float* __restrict__ u, const float* __restrict__ Dp,
                       float* __restrict__ S)
{
    int li = blockIdx.x * 256 + threadIdx.x;
    int c = blockIdx.y;
    int b = li >> 11, l = li & (SEQLEN - 1);
    const float* up = u + (long long)b * D_INNER * SEQLEN + l;
    float acc = 0.f;
    for (int d = c * 256; d < c * 256 + 256; ++d)
        acc += Dp[d] * up[(long long)d * SEQLEN];
    atomicAdd(&S[li], acc);
}

// ---------------- y=(y+Dp*u)*silu(z), transposed into ycat16[...,:2048] -------
__global__ __launch_bounds__(256) void ytrans_k(const float* __restrict__ ysc,
    const float* __restrict__ u, const float* __restrict__ xz,
    const float* __restrict__ Dp, __bf16* __restrict__ ycat)
{
    __shared__ float tile[32][33];
    const int b = blockIdx.z;
    const int d0 = blockIdx.y * 32, l0 = blockIdx.x * 32;
    const int lx = threadIdx.x, dy = threadIdx.y;
    #pragma unroll
    for (int j = 0; j < 4; ++j) {
        int d = d0 + dy + j * 8;
        long long i  = ((long long)b * D_INNER + d) * SEQLEN + l0 + lx;
        long long iz = ((long long)b * 2 * D_INNER + D_INNER + d) * SEQLEN + l0 + lx;
        tile[dy + j * 8][lx] = (ysc[i] + Dp[d] * u[i]) * silu_f(xz[iz]);
    }
    __syncthreads();
    #pragma unroll
    for (int j = 0; j < 4; ++j) {
        int l = l0 + dy + j * 8;
        ycat[((long long)b * SEQLEN + l) * (2 * D_INNER) + d0 + lx] = (__bf16)tile[lx][dy + j * 8];
    }
}

// ---------------- y_t -> ycat16[...,2048:] ----------------
__global__ __launch_bounds__(256) void yt_k(const float* __restrict__ xdbl,
    const float* __restrict__ Aneg, const float* __restrict__ S, __bf16* __restrict__ ycat)
{
    __shared__ float Cs[16][33];
    __shared__ float An[16][64];
    __shared__ float Sv[32];
    const int b = blockIdx.z;
    const int d0 = blockIdx.y * 64, l0 = blockIdx.x * 32;
    const int tid = threadIdx.x;
    for (int f = tid; f < 512; f += 256) {
        int n = f & 15, l = f >> 4;
        Cs[n][l] = xdbl[((long long)b * SEQLEN + l0 + l) * XSTR + DT_RANK + D_STATE + n];
    }
    for (int f = tid; f < 1024; f += 256) {
        int n = f & 15, d = f >> 4;
        An[n][d] = Aneg[(d0 + d) * D_STATE + n];
    }
    if (tid < 32) Sv[tid] = S[b * SEQLEN + l0 + tid];
    __syncthreads();
    const int dx = tid & 63, lg = tid >> 6;
    #pragma unroll
    for (int j = 0; j < 8; ++j) {
        int l = lg * 8 + j;
        float acc = Sv[l];
        #pragma unroll
        for (int n = 0; n < 16; ++n) acc += Cs[n][l] * An[n][dx];
        ycat[((long long)b * SEQLEN + l0 + l) * (2 * D_INNER) + D_INNER + d0 + dx] = (__bf16)acc;
    }
}

extern "C" void kernel_launch(void* const* d_in, const int* in_sizes, int n_in,
                              void* d_out, int out_size, void* d_ws, size_t ws_size,
                              hipStream_t stream)
{
    const float* x      = (const float*)d_in[0];
    const float* W_in   = (const float*)d_in[1];
    const float* conv_w = (const float*)d_in[2];
    const float* conv_b = (const float*)d_in[3];
    const float* W_x    = (const float*)d_in[4];
    const float* W_dt   = (const float*)d_in[5];
    const float* b_dt   = (const float*)d_in[6];
    const float* A_log  = (const float*)d_in[7];
    const float* Dp     = (const float*)d_in[8];
    const float* W_out1 = (const float*)d_in[9];
    const float* W_out2 = (const float*)d_in[10];
    float* out = (float*)d_out;
    float* ws  = (float*)d_ws;

    // fp32 region (~170 MB)
    float* xz    = ws;                    // 16777216
    float* u     = xz    + 16777216;      //  8388608
    float* xdblp = u     + 8388608;       //   524288 (B*L x 128 padded)
    float* dtb   = xdblp + 524288;        //  8388608 (delta)
    float* ysc   = dtb   + 8388608;       //  8388608
    float* Aneg  = ysc   + 8388608;       //    32768
    float* S     = Aneg  + 32768;         //     4096
    // bf16 tail (50.3 MB)
    __bf16* ycat16 = (__bf16*)(S + 4096);          // 16777216 el
    __bf16* h16    = ycat16 + 16777216;            //  8388608 el
    // overlays (regions dead at time of use)
    __bf16* W_in16  = (__bf16*)u;                  // before conv writes u
    __bf16* xb16    = W_in16 + 4194304;
    __bf16* Wout116 = (__bf16*)dtb;                // after scan reads dtb
    __bf16* Wout216 = Wout116 + 8388608;
    // u_t (bf16 [B*L][D_INNER], 16.8MB) inside ycat16 (33.5MB)
    __bf16* ut16  = ycat16;                        // 8388608 el
    // Wx bf16 padded [128][2048] inside h16 region (dead until out1 GEMM)
    __bf16* Wx16p = h16;                           // 262144 el
    // x_dbl K-split partials overlay dtb (dead until dt GEMM)
    float* xpart  = dtb;

    hipMemsetAsync(S, 0, 4096 * sizeof(float), stream);
    aneg_k<<<128, 256, 0, stream>>>(A_log, Aneg);

    // bf16 conversions for input GEMM
    cvt_bf16_k<<<2048, 256, 0, stream>>>(W_in, W_in16, 524288);
    cvt_bf16_k<<<2048, 256, 0, stream>>>(x, xb16, 524288);
    // W_x -> bf16 (96 rows), zero-pad rows 96..127
    cvt_bf16_k<<<96, 256, 0, stream>>>(W_x, Wx16p, 24576);
    hipMemsetAsync(Wx16p + 96 * D_INNER, 0, 32 * D_INNER * sizeof(__bf16), stream);

    // xz[b,e,l] = sum_d W_in[e,d] * x[b,l,d]   (M=4096, N=2048, K=1024)
    gemm_bf16_k<0, 0><<<dim3(16, 32, BATCH), 256, 0, stream>>>(
        W_in16, xb16, xz, D_MODEL, D_MODEL, D_MODEL, SEQLEN,
        0LL, (long long)SEQLEN * D_MODEL, (long long)4096 * SEQLEN);

    conv_silu_k<<<dim3(SEQLEN / 32, D_INNER / 32, BATCH), dim3(32, 8), 0, stream>>>(
        xz, conv_w, conv_b, u, ut16);

    // x_dbl partials: K-split=8 (z selects k-range via sA/sB), 256 blocks
    gemm_bf16_k<0, 0><<<dim3(1, 32, XKS), 256, 0, stream>>>(
        ut16, Wx16p, xpart, D_INNER / XKS, D_INNER, D_INNER, XSTR,
        (long long)(D_INNER / XKS), (long long)(D_INNER / XKS),
        (long long)BATCH * SEQLEN * XSTR);
    xdbl_red_k<<<(BATCH * SEQLEN * XSTR / 4) / 256, 256, 0, stream>>>(xpart, xdblp);

    // dt[b,d,l] = softplus(sum_r W_dt[d,r] * x_dbl[b,l,r] + b_dt[d])  (fused)
    gemm_nt_k<1><<<dim3(SEQLEN / 64, D_INNER / 64, BATCH), 256, 0, stream>>>(
        W_dt, xdblp, dtb, b_dt, D_INNER, SEQLEN, DT_RANK, DT_RANK, XSTR, SEQLEN,
        0LL, (long long)SEQLEN * XSTR, (long long)D_INNER * SEQLEN);

    // fused chunked scan: one block per chain
    scan_f_k<<<BATCH * D_INNER, 256, 0, stream>>>(dtb, u, xdblp, Aneg, ysc);

    // weight conversions for output GEMMs (dtb region dead now)
    cvt_bf16_k<<<4096, 256, 0, stream>>>(W_out1, Wout116, 1048576);
    cvt_bf16_k<<<1024, 256, 0, stream>>>(W_out2, Wout216, 262144);

    ssum_k<<<dim3((BATCH * SEQLEN) / 256, 8), 256, 0, stream>>>(u, Dp, S);

    ytrans_k<<<dim3(SEQLEN / 32, D_INNER / 32, BATCH), dim3(32, 8), 0, stream>>>(ysc, u, xz, Dp, ycat16);

    yt_k<<<dim3(SEQLEN / 32, D_INNER / 64, BATCH), 256, 0, stream>>>(xdblp, Aneg, S, ycat16);

    // h = relu(ycat @ W_out1^T) -> bf16   (M=4096, N=2048, K=4096)
    gemm_bf16_k<1, 1><<<dim3(16, 32, 1), 256, 0, stream>>>(
        ycat16, Wout116, h16, 2 * D_INNER, 2 * D_INNER, 2 * D_INNER, D_INNER,
        0LL, 0LL, 0LL);

    // out = h @ W_out2^T   (M=4096, N=1024, K=2048)
    gemm_bf16_k<0, 0><<<dim3(8, 32, 1), 256, 0, stream>>>(
        h16, Wout216, out, D_INNER, D_INNER, D_INNER, D_MODEL,
        0LL, 0LL, 0LL);
}

// Round 16
// 529.913 us; speedup vs baseline: 1.5576x; 1.0274x over previous
//
#include <hip/hip_runtime.h>
#include <hip/hip_bf16.h>
#include <math.h>

#define D_MODEL 1024
#define D_STATE 16
#define D_INNER 2048
#define DT_RANK 64
#define BATCH   2
#define SEQLEN  2048
#define NPROJ   96   // DT_RANK + 2*D_STATE (logical)
#define XSTR    128  // padded x_dbl row stride
#define NCHUNK  16
#define CHUNK   128  // SEQLEN / NCHUNK
#define XKS     8    // x_dbl GEMM K-split

typedef __attribute__((ext_vector_type(8))) __bf16 bf16x8;
typedef __attribute__((ext_vector_type(4))) float f32x4;

__device__ __forceinline__ float silu_f(float x) { return x / (1.f + __expf(-x)); }

__device__ __forceinline__ void gload_lds16(const void* g, void* l) {
    __builtin_amdgcn_global_load_lds((const __attribute__((address_space(1))) void*)g,
                                     (__attribute__((address_space(3))) void*)l, 16, 0, 0);
}

// ---------------- bf16 MFMA NT GEMM: C[m,n] = sum_k A[m,k]*B[n,k] -------------
// 128x128 tile, BK=32, 4 waves. Bijective XCD swizzle on (y,x) flat id.
template<int RELU, int OUT_BF16>
__global__ __launch_bounds__(256) void gemm_bf16_k(
    const __bf16* __restrict__ A, const __bf16* __restrict__ B, void* __restrict__ Cv,
    int K, int lda, int ldb, int ldc, long long sA, long long sB, long long sC)
{
    __shared__ alignas(16) __bf16 As[128 * 32];
    __shared__ alignas(16) __bf16 Bs[128 * 32];
    const int bz = blockIdx.z;
    A += (long long)bz * sA;
    B += (long long)bz * sB;
    int nwg = gridDim.x * gridDim.y;
    int flat = blockIdx.y * gridDim.x + blockIdx.x;
    int swz = (nwg & 7) ? flat : ((flat & 7) * (nwg >> 3) + (flat >> 3));
    const int m0 = (swz / gridDim.x) * 128, n0 = (swz % gridDim.x) * 128;
    const int tid = threadIdx.x;
    const int lane = tid & 63;
    const int wv = tid >> 6;
    const int wr = wv >> 1, wc = wv & 1;

    f32x4 acc[4][4];
    #pragma unroll
    for (int i = 0; i < 4; ++i)
        #pragma unroll
        for (int j = 0; j < 4; ++j) acc[i][j] = (f32x4){0.f, 0.f, 0.f, 0.f};

    const int ko = (lane >> 4) * 8;
    const int fr = lane & 15;

    for (int k0 = 0; k0 < K; k0 += 32) {
        #pragma unroll
        for (int q = 0; q < 2; ++q) {
            int f = tid + q * 256;
            int row = f >> 2, c16 = f & 3;
            gload_lds16(A + (long long)(m0 + row) * lda + k0 + c16 * 8, As + f * 8);
            gload_lds16(B + (long long)(n0 + row) * ldb + k0 + c16 * 8, Bs + f * 8);
        }
        __syncthreads();
        bf16x8 a[4], b[4];
        #pragma unroll
        for (int i = 0; i < 4; ++i) {
            a[i] = *(const bf16x8*)(As + (wr * 64 + i * 16 + fr) * 32 + ko);
            b[i] = *(const bf16x8*)(Bs + (wc * 64 + i * 16 + fr) * 32 + ko);
        }
        #pragma unroll
        for (int i = 0; i < 4; ++i)
            #pragma unroll
            for (int j = 0; j < 4; ++j)
                acc[i][j] = __builtin_amdgcn_mfma_f32_16x16x32_bf16(a[i], b[j], acc[i][j], 0, 0, 0);
        __syncthreads();
    }

    #pragma unroll
    for (int i = 0; i < 4; ++i) {
        const int row = m0 + wr * 64 + i * 16 + (lane >> 4) * 4;
        #pragma unroll
        for (int j = 0; j < 4; ++j) {
            const int col = n0 + wc * 64 + j * 16 + fr;
            #pragma unroll
            for (int r = 0; r < 4; ++r) {
                float v = acc[i][j][r];
                if (RELU) v = fmaxf(v, 0.f);
                if (OUT_BF16)
                    ((__bf16*)Cv)[(long long)bz * sC + (long long)(row + r) * ldc + col] = (__bf16)v;
                else
                    ((float*)Cv)[(long long)bz * sC + (long long)(row + r) * ldc + col] = v;
            }
        }
    }
}

// ---------------- f32 -> bf16 pack (8 per thread) ----------------
__global__ void cvt_bf16_k(const float* __restrict__ in, __bf16* __restrict__ out, int n8) {
    int i = blockIdx.x * 256 + threadIdx.x;
    if (i >= n8) return;
    const f32x4* p = (const f32x4*)in + (long long)i * 2;
    f32x4 v0 = p[0], v1 = p[1];
    bf16x8 o;
    o[0] = (__bf16)v0[0]; o[1] = (__bf16)v0[1]; o[2] = (__bf16)v0[2]; o[3] = (__bf16)v0[3];
    o[4] = (__bf16)v1[0]; o[5] = (__bf16)v1[1]; o[6] = (__bf16)v1[2]; o[7] = (__bf16)v1[3];
    ((bf16x8*)out)[i] = o;
}

// ---------------- generic fp32 NT GEMM (dt GEMM; fused softplus) --------------
template<int SOFTPLUS>
__global__ __launch_bounds__(256) void gemm_nt_k(
    const float* __restrict__ A, const float* __restrict__ B, float* __restrict__ C,
    const float* __restrict__ bias,
    int M, int N, int K, int lda, int ldb, int ldc,
    long long sA, long long sB, long long sC)
{
    __shared__ float As[16][68];
    __shared__ float Bs[16][68];
    const int bz = blockIdx.z;
    A += (long long)bz * sA; B += (long long)bz * sB; C += (long long)bz * sC;
    const int m0 = blockIdx.y * 64, n0 = blockIdx.x * 64;
    const int tid = threadIdx.x;
    const int lk = tid & 15, lr = tid >> 4;
    const int tx = tid & 15, ty = tid >> 4;
    float acc[4][4] = {};
    for (int k0 = 0; k0 < K; k0 += 16) {
        #pragma unroll
        for (int q = 0; q < 4; ++q) {
            int i = lr + q * 16;
            As[lk][i] = A[(long long)(m0 + i) * lda + k0 + lk];
            Bs[lk][i] = B[(long long)(n0 + i) * ldb + k0 + lk];
        }
        __syncthreads();
        #pragma unroll
        for (int k = 0; k < 16; ++k) {
            float a[4], b[4];
            #pragma unroll
            for (int j = 0; j < 4; ++j) { a[j] = As[k][ty*4+j]; b[j] = Bs[k][tx*4+j]; }
            #pragma unroll
            for (int i = 0; i < 4; ++i)
                #pragma unroll
                for (int j = 0; j < 4; ++j) acc[i][j] += a[i] * b[j];
        }
        __syncthreads();
    }
    #pragma unroll
    for (int i = 0; i < 4; ++i) {
        const int m = m0 + ty * 4 + i;
        float bi = SOFTPLUS ? bias[m] : 0.f;
        #pragma unroll
        for (int j = 0; j < 4; ++j) {
            float v = acc[i][j];
            if (SOFTPLUS) {
                v += bi;
                v = fmaxf(v, 0.f) + log1pf(expf(-fabsf(v)));
            }
            C[(long long)m * ldc + n0 + tx*4 + j] = v;
        }
    }
}

// ---------------- Aneg = -exp(A_log) ----------------
__global__ void aneg_k(const float* __restrict__ A_log, float* __restrict__ Aneg) {
    int i = blockIdx.x * 256 + threadIdx.x;
    if (i < D_INNER * D_STATE) Aneg[i] = -expf(A_log[i]);
}

// ---------------- depthwise causal conv(4) + bias + SiLU, dual-layout out -----
__global__ __launch_bounds__(256) void conv_silu_k(const float* __restrict__ xz,
    const float* __restrict__ cw, const float* __restrict__ cb,
    float* __restrict__ u, __bf16* __restrict__ ut)
{
    __shared__ float tile[32][33];
    const int b = blockIdx.z;
    const int d0 = blockIdx.y * 32, l0 = blockIdx.x * 32;
    const int lx = threadIdx.x, dy = threadIdx.y;   // (32,8)
    #pragma unroll
    for (int j = 0; j < 4; ++j) {
        int d = d0 + dy + j * 8;
        const float* xi = xz + ((long long)b * 2 * D_INNER + d) * SEQLEN;
        int l = l0 + lx;
        float acc = cb[d];
        #pragma unroll
        for (int k = 0; k < 4; ++k) {
            int t = l + k - 3;
            if (t >= 0) acc += xi[t] * cw[d * 4 + k];
        }
        float v = silu_f(acc);
        u[((long long)b * D_INNER + d) * SEQLEN + l] = v;
        tile[dy + j * 8][lx] = v;
    }
    __syncthreads();
    #pragma unroll
    for (int j = 0; j < 4; ++j) {
        int l = l0 + dy + j * 8;
        ut[((long long)b * SEQLEN + l) * D_INNER + d0 + lx] = (__bf16)tile[lx][dy + j * 8];
    }
}

// ---------------- reduce XKS x_dbl partials -> xdblp ----------------
__global__ void xdbl_red_k(const float* __restrict__ xpart, float* __restrict__ xdbl) {
    int i = blockIdx.x * 256 + threadIdx.x;
    const f32x4* p = (const f32x4*)xpart;
    f32x4 s = p[i];
    #pragma unroll
    for (int ks = 1; ks < XKS; ++ks) {
        f32x4 v = p[(long long)ks * (BATCH * SEQLEN * XSTR / 4) + i];
        s.x += v.x; s.y += v.y; s.z += v.z; s.w += v.w;
    }
    ((f32x4*)xdbl)[i] = s;
}

// ======== fused chunked selective scan: one block per chain ===================
// 256 threads = 4 waves; WAVE-LOCAL chunks: wave w owns chunks 4w..4w+3
// (lane = q*16+n, c = w*4+q). The pass-2 lp write->read transpose is then
// same-wave (compiler lgkmcnt orders it) -> NO barriers in the main loops.
// Only 2 barriers remain, around the LDS combine.
__global__ __launch_bounds__(256) void scan_f_k(const float* __restrict__ delta,
    const float* __restrict__ u, const float* __restrict__ xdbl,
    const float* __restrict__ Aneg, float* __restrict__ y)
{
    __shared__ float combA[NCHUNK][16];
    __shared__ float combS[NCHUNK][16];
    __shared__ float sins[NCHUNK][16];
    __shared__ float lp[NCHUNK][16][17];
    const int tid = threadIdx.x;
    const int lane = tid & 63;
    const int n = lane & 15;
    const int c = (tid >> 6) * 4 + (lane >> 4);   // wave-local chunk id
    const int g = blockIdx.x;                     // chain id = b*D_INNER + d
    const int b = g >> 11, d = g & (D_INNER - 1);
    const float a = Aneg[d * D_STATE + n];
    const long long base = (long long)g * SEQLEN + c * CHUNK;
    const float4* dv = (const float4*)(delta + base);
    const float4* uv = (const float4*)(u + base);
    const float* xb = xdbl + ((long long)b * SEQLEN + c * CHUNK) * XSTR + DT_RANK + n;

    // ---- pass 1: chunk-local scan from 0, accumulate A = prod dA ----
    float4 pd[4], pu[4];
    float pB[16];
    #pragma unroll
    for (int i = 0; i < 4; ++i) { pd[i] = dv[i]; pu[i] = uv[i]; }
    #pragma unroll
    for (int i = 0; i < 16; ++i) pB[i] = xb[i * XSTR];

    float s = 0.f, ap = 1.f;
    for (int t0 = 0; t0 < CHUNK; t0 += 16) {
        float cd[16], cu[16], cB[16];
        #pragma unroll
        for (int i = 0; i < 4; ++i) {
            cd[4*i] = pd[i].x; cd[4*i+1] = pd[i].y; cd[4*i+2] = pd[i].z; cd[4*i+3] = pd[i].w;
            cu[4*i] = pu[i].x; cu[4*i+1] = pu[i].y; cu[4*i+2] = pu[i].z; cu[4*i+3] = pu[i].w;
        }
        #pragma unroll
        for (int i = 0; i < 16; ++i) cB[i] = pB[i];
        if (t0 + 16 < CHUNK) {
            const int nb = (t0 >> 2) + 4;
            #pragma unroll
            for (int i = 0; i < 4; ++i) { pd[i] = dv[nb + i]; pu[i] = uv[nb + i]; }
            const float* xn = xb + (t0 + 16) * XSTR;
            #pragma unroll
            for (int i = 0; i < 16; ++i) pB[i] = xn[i * XSTR];
        }
        float dA[16], wB[16];
        #pragma unroll
        for (int i = 0; i < 16; ++i) {
            dA[i] = __expf(cd[i] * a);
            wB[i] = cd[i] * cu[i] * cB[i];
        }
        #pragma unroll
        for (int i = 0; i < 16; ++i) {
            s = dA[i] * s + wB[i];
            ap *= dA[i];
        }
    }
    combA[c][n] = ap;
    combS[c][n] = s;
    __syncthreads();

    // ---- combine: 16 threads do the serial 16-chunk prefix ----
    if (tid < 16) {
        float av[NCHUNK], sv[NCHUNK];
        #pragma unroll
        for (int cc = 0; cc < NCHUNK; ++cc) { av[cc] = combA[cc][tid]; sv[cc] = combS[cc][tid]; }
        float carry = 0.f;
        #pragma unroll
        for (int cc = 0; cc < NCHUNK; ++cc) {
            sins[cc][tid] = carry;
            carry = sv[cc] + av[cc] * carry;
        }
    }
    __syncthreads();

    // ---- pass 2: re-scan from sinit, emit y (no barriers: same-wave LDS) ----
    float* yl = y + base;
    float pC[16];
    #pragma unroll
    for (int i = 0; i < 4; ++i) { pd[i] = dv[i]; pu[i] = uv[i]; }
    #pragma unroll
    for (int i = 0; i < 16; ++i) { pB[i] = xb[i * XSTR]; pC[i] = xb[i * XSTR + D_STATE]; }

    s = sins[c][n];
    for (int t0 = 0; t0 < CHUNK; t0 += 16) {
        float cd[16], cu[16], cB[16], cC[16];
        #pragma unroll
        for (int i = 0; i < 4; ++i) {
            cd[4*i] = pd[i].x; cd[4*i+1] = pd[i].y; cd[4*i+2] = pd[i].z; cd[4*i+3] = pd[i].w;
            cu[4*i] = pu[i].x; cu[4*i+1] = pu[i].y; cu[4*i+2] = pu[i].z; cu[4*i+3] = pu[i].w;
        }
        #pragma unroll
        for (int i = 0; i < 16; ++i) { cB[i] = pB[i]; cC[i] = pC[i]; }
        if (t0 + 16 < CHUNK) {
            const int nb = (t0 >> 2) + 4;
            #pragma unroll
            for (int i = 0; i < 4; ++i) { pd[i] = dv[nb + i]; pu[i] = uv[nb + i]; }
            const float* xn = xb + (t0 + 16) * XSTR;
            #pragma unroll
            for (int i = 0; i < 16; ++i) { pB[i] = xn[i * XSTR]; pC[i] = xn[i * XSTR + D_STATE]; }
        }
        float dA[16], wB[16];
        #pragma unroll
        for (int i = 0; i < 16; ++i) {
            dA[i] = __expf(cd[i] * a);
            wB[i] = cd[i] * cu[i] * cB[i];
        }
        #pragma unroll
        for (int i = 0; i < 16; ++i) {
            s = dA[i] * s + wB[i];
            lp[c][n][i] = s * cC[i];
        }
        // same-wave transpose-reduce (lgkmcnt-ordered, no barrier)
        float v[16];
        #pragma unroll
        for (int j = 0; j < 16; ++j) v[j] = lp[c][j][n];
        float acc = 0.f;
        #pragma unroll
        for (int j = 0; j < 16; ++j) acc += v[j];
        yl[t0 + n] = acc;
    }
}

// ---------------- S[b,l] = sum_d Dp[d]*u[b,d,l] ----------------
__global__ void ssum_k(const float* __restrict__ u, const float* __restrict__ Dp,
                       float* __restrict__ S)
{
    int li = blockIdx.x * 256 + threadIdx.x;
    int c = blockIdx.y;
    int b = li >> 11, l = li & (SEQLEN - 1);
    const float* up = u + (long long)b * D_INNER * SEQLEN + l;
    float acc = 0.f;
    for (int d = c * 256; d < c * 256 + 256; ++d)
        acc += Dp[d] * up[(long long)d * SEQLEN];
    atomicAdd(&S[li], acc);
}

// ---------------- y=(y+Dp*u)*silu(z), transposed into ycat16[...,:2048] -------
__global__ __launch_bounds__(256) void ytrans_k(const float* __restrict__ ysc,
    const float* __restrict__ u, const float* __restrict__ xz,
    const float* __restrict__ Dp, __bf16* __restrict__ ycat)
{
    __shared__ float tile[32][33];
    const int b = blockIdx.z;
    const int d0 = blockIdx.y * 32, l0 = blockIdx.x * 32;
    const int lx = threadIdx.x, dy = threadIdx.y;
    #pragma unroll
    for (int j = 0; j < 4; ++j) {
        int d = d0 + dy + j * 8;
        long long i  = ((long long)b * D_INNER + d) * SEQLEN + l0 + lx;
        long long iz = ((long long)b * 2 * D_INNER + D_INNER + d) * SEQLEN + l0 + lx;
        tile[dy + j * 8][lx] = (ysc[i] + Dp[d] * u[i]) * silu_f(xz[iz]);
    }
    __syncthreads();
    #pragma unroll
    for (int j = 0; j < 4; ++j) {
        int l = l0 + dy + j * 8;
        ycat[((long long)b * SEQLEN + l) * (2 * D_INNER) + d0 + lx] = (__bf16)tile[lx][dy + j * 8];
    }
}

// ---------------- y_t -> ycat16[...,2048:] ----------------
__global__ __launch_bounds__(256) void yt_k(const float* __restrict__ xdbl,
    const float* __restrict__ Aneg, const float* __restrict__ S, __bf16* __restrict__ ycat)
{
    __shared__ float Cs[16][33];
    __shared__ float An[16][64];
    __shared__ float Sv[32];
    const int b = blockIdx.z;
    const int d0 = blockIdx.y * 64, l0 = blockIdx.x * 32;
    const int tid = threadIdx.x;
    for (int f = tid; f < 512; f += 256) {
        int n = f & 15, l = f >> 4;
        Cs[n][l] = xdbl[((long long)b * SEQLEN + l0 + l) * XSTR + DT_RANK + D_STATE + n];
    }
    for (int f = tid; f < 1024; f += 256) {
        int n = f & 15, d = f >> 4;
        An[n][d] = Aneg[(d0 + d) * D_STATE + n];
    }
    if (tid < 32) Sv[tid] = S[b * SEQLEN + l0 + tid];
    __syncthreads();
    const int dx = tid & 63, lg = tid >> 6;
    #pragma unroll
    for (int j = 0; j < 8; ++j) {
        int l = lg * 8 + j;
        float acc = Sv[l];
        #pragma unroll
        for (int n = 0; n < 16; ++n) acc += Cs[n][l] * An[n][dx];
        ycat[((long long)b * SEQLEN + l0 + l) * (2 * D_INNER) + D_INNER + d0 + dx] = (__bf16)acc;
    }
}

extern "C" void kernel_launch(void* const* d_in, const int* in_sizes, int n_in,
                              void* d_out, int out_size, void* d_ws, size_t ws_size,
                              hipStream_t stream)
{
    const float* x      = (const float*)d_in[0];
    const float* W_in   = (const float*)d_in[1];
    const float* conv_w = (const float*)d_in[2];
    const float* conv_b = (const float*)d_in[3];
    const float* W_x    = (const float*)d_in[4];
    const float* W_dt   = (const float*)d_in[5];
    const float* b_dt   = (const float*)d_in[6];
    const float* A_log  = (const float*)d_in[7];
    const float* Dp     = (const float*)d_in[8];
    const float* W_out1 = (const float*)d_in[9];
    const float* W_out2 = (const float*)d_in[10];
    float* out = (float*)d_out;
    float* ws  = (float*)d_ws;

    // fp32 region (~170 MB)
    float* xz    = ws;                    // 16777216
    float* u     = xz    + 16777216;      //  8388608
    float* xdblp = u     + 8388608;       //   524288 (B*L x 128 padded)
    float* dtb   = xdblp + 524288;        //  8388608 (delta)
    float* ysc   = dtb   + 8388608;       //  8388608
    float* Aneg  = ysc   + 8388608;       //    32768
    float* S     = Aneg  + 32768;         //     4096
    // bf16 tail (50.3 MB)
    __bf16* ycat16 = (__bf16*)(S + 4096);          // 16777216 el
    __bf16* h16    = ycat16 + 16777216;            //  8388608 el
    // overlays (regions dead at time of use)
    __bf16* W_in16  = (__bf16*)u;                  // before conv writes u
    __bf16* xb16    = W_in16 + 4194304;
    __bf16* Wout116 = (__bf16*)dtb;                // after scan reads dtb
    __bf16* Wout216 = Wout116 + 8388608;
    // u_t (bf16 [B*L][D_INNER], 16.8MB) inside ycat16 (33.5MB)
    __bf16* ut16  = ycat16;                        // 8388608 el
    // Wx bf16 padded [128][2048] inside h16 region (dead until out1 GEMM)
    __bf16* Wx16p = h16;                           // 262144 el
    // x_dbl K-split partials overlay dtb (dead until dt GEMM)
    float* xpart  = dtb;

    hipMemsetAsync(S, 0, 4096 * sizeof(float), stream);
    aneg_k<<<128, 256, 0, stream>>>(A_log, Aneg);

    // bf16 conversions for input GEMM
    cvt_bf16_k<<<2048, 256, 0, stream>>>(W_in, W_in16, 524288);
    cvt_bf16_k<<<2048, 256, 0, stream>>>(x, xb16, 524288);
    // W_x -> bf16 (96 rows), zero-pad rows 96..127
    cvt_bf16_k<<<96, 256, 0, stream>>>(W_x, Wx16p, 24576);
    hipMemsetAsync(Wx16p + 96 * D_INNER, 0, 32 * D_INNER * sizeof(__bf16), stream);

    // xz[b,e,l] = sum_d W_in[e,d] * x[b,l,d]   (M=4096, N=2048, K=1024)
    gemm_bf16_k<0, 0><<<dim3(16, 32, BATCH), 256, 0, stream>>>(
        W_in16, xb16, xz, D_MODEL, D_MODEL, D_MODEL, SEQLEN,
        0LL, (long long)SEQLEN * D_MODEL, (long long)4096 * SEQLEN);

    conv_silu_k<<<dim3(SEQLEN / 32, D_INNER / 32, BATCH), dim3(32, 8), 0, stream>>>(
        xz, conv_w, conv_b, u, ut16);

    // x_dbl partials: K-split=8 (z selects k-range via sA/sB), 256 blocks
    gemm_bf16_k<0, 0><<<dim3(1, 32, XKS), 256, 0, stream>>>(
        ut16, Wx16p, xpart, D_INNER / XKS, D_INNER, D_INNER, XSTR,
        (long long)(D_INNER / XKS), (long long)(D_INNER / XKS),
        (long long)BATCH * SEQLEN * XSTR);
    xdbl_red_k<<<(BATCH * SEQLEN * XSTR / 4) / 256, 256, 0, stream>>>(xpart, xdblp);

    // dt[b,d,l] = softplus(sum_r W_dt[d,r] * x_dbl[b,l,r] + b_dt[d])  (fused)
    gemm_nt_k<1><<<dim3(SEQLEN / 64, D_INNER / 64, BATCH), 256, 0, stream>>>(
        W_dt, xdblp, dtb, b_dt, D_INNER, SEQLEN, DT_RANK, DT_RANK, XSTR, SEQLEN,
        0LL, (long long)SEQLEN * XSTR, (long long)D_INNER * SEQLEN);

    // fused chunked scan: one block per chain
    scan_f_k<<<BATCH * D_INNER, 256, 0, stream>>>(dtb, u, xdblp, Aneg, ysc);

    // weight conversions for output GEMMs (dtb region dead now)
    cvt_bf16_k<<<4096, 256, 0, stream>>>(W_out1, Wout116, 1048576);
    cvt_bf16_k<<<1024, 256, 0, stream>>>(W_out2, Wout216, 262144);

    ssum_k<<<dim3((BATCH * SEQLEN) / 256, 8), 256, 0, stream>>>(u, Dp, S);

    ytrans_k<<<dim3(SEQLEN / 32, D_INNER / 32, BATCH), dim3(32, 8), 0, stream>>>(ysc, u, xz, Dp, ycat16);

    yt_k<<<dim3(SEQLEN / 32, D_INNER / 64, BATCH), 256, 0, stream>>>(xdblp, Aneg, S, ycat16);

    // h = relu(ycat @ W_out1^T) -> bf16   (M=4096, N=2048, K=4096)
    gemm_bf16_k<1, 1><<<dim3(16, 32, 1), 256, 0, stream>>>(
        ycat16, Wout116, h16, 2 * D_INNER, 2 * D_INNER, 2 * D_INNER, D_INNER,
        0LL, 0LL, 0LL);

    // out = h @ W_out2^T   (M=4096, N=1024, K=2048)
    gemm_bf16_k<0, 0><<<dim3(8, 32, 1), 256, 0, stream>>>(
        h16, Wout216, out, D_INNER, D_INNER, D_INNER, D_MODEL,
        0LL, 0LL, 0LL);
}